// Round 11
// baseline (941.625 us; speedup 1.0000x reference)
//
#include <hip/hip_runtime.h>
#include <math.h>

typedef short bf16x8 __attribute__((ext_vector_type(8)));
typedef float f32x4  __attribute__((ext_vector_type(4)));

__device__ __forceinline__ unsigned short f2bf(float x) {
    unsigned u = __float_as_uint(x);
    unsigned r = u + 0x7FFFu + ((u >> 16) & 1u);   // RNE
    return (unsigned short)(r >> 16);
}
__device__ __forceinline__ float bf2f(unsigned short b) {
    return __uint_as_float(((unsigned)b) << 16);
}
__device__ __forceinline__ bf16x8 ld_f32x8_as_bf(const float* p) {
    float4 a = *(const float4*)p;
    float4 b = *(const float4*)(p + 4);
    bf16x8 v;
    v[0] = (short)f2bf(a.x); v[1] = (short)f2bf(a.y);
    v[2] = (short)f2bf(a.z); v[3] = (short)f2bf(a.w);
    v[4] = (short)f2bf(b.x); v[5] = (short)f2bf(b.y);
    v[6] = (short)f2bf(b.z); v[7] = (short)f2bf(b.w);
    return v;
}

// ============ weight convert+transpose: Wt[n][k] = bf16(W[k][n]) ============
__global__ __launch_bounds__(256)
void wconv(const float* __restrict__ W, unsigned short* __restrict__ Wt, int K, int N)
{
    int id = blockIdx.x * 256 + threadIdx.x;
    if (id >= K * N) return;
    int n = id / K, k = id - n * K;
    Wt[(size_t)n * K + k] = f2bf(W[(size_t)k * N + n]);
}

// ============ bulk f32 -> bf16 (for feat; streams at HBM BW) ============
__global__ __launch_bounds__(256)
void f32_to_bf16(const float* __restrict__ in, unsigned short* __restrict__ outb, long n8)
{
    long id = (long)blockIdx.x * 256 + threadIdx.x;   // one per 8 elems
    if (id >= n8) return;
    const float4* p = (const float4*)(in + id * 8);
    float4 a = p[0], b = p[1];
    *(ushort4*)(outb + id * 8)     = make_ushort4(f2bf(a.x), f2bf(a.y), f2bf(a.z), f2bf(a.w));
    *(ushort4*)(outb + id * 8 + 4) = make_ushort4(f2bf(b.x), f2bf(b.y), f2bf(b.z), f2bf(b.w));
}

// ============ LDS-free MFMA GEMM, low-acc tiling for occupancy ============
// A bf16 [M,K]; Wt bf16 [Ncols][K]. Wave tile 32x64 (acc = 32 AGPR).
// Block = 4 waves (2 row-groups x 2 col-groups) -> 64 rows x 128 cols.
__global__ __launch_bounds__(256)
void mfma_direct(const unsigned short* __restrict__ Ab, const unsigned short* __restrict__ Wt,
                 const float* __restrict__ bias, unsigned short* __restrict__ out_bf,
                 int M, int K, int Ncols)
{
    const int tid  = threadIdx.x;
    const int row0 = blockIdx.x * 64;
    const int col0 = blockIdx.y * 128;
    const int wv   = tid >> 6, lane = tid & 63;
    const int wr   = (wv >> 1) * 32, wc = (wv & 1) * 64;
    const int lr   = lane & 15;
    const int lk8  = (lane >> 4) * 8;

    const unsigned short* arow[2];
    const unsigned short* brow[4];
#pragma unroll
    for (int m = 0; m < 2; m++) {
        int r = row0 + wr + m * 16 + lr;
        r = r < M ? r : (M - 1);
        arow[m] = Ab + (size_t)r * K + lk8;
    }
#pragma unroll
    for (int n = 0; n < 4; n++)
        brow[n] = Wt + (size_t)(col0 + wc + n * 16 + lr) * K + lk8;

    f32x4 acc[2][4];
#pragma unroll
    for (int m = 0; m < 2; m++)
#pragma unroll
        for (int n = 0; n < 4; n++)
#pragma unroll
            for (int j = 0; j < 4; j++) acc[m][n][j] = 0.f;

#pragma unroll 2
    for (int kk = 0; kk < K; kk += 32) {
        bf16x8 af[2], bfr[4];
#pragma unroll
        for (int m = 0; m < 2; m++) af[m]  = *(const bf16x8*)(arow[m] + kk);
#pragma unroll
        for (int n = 0; n < 4; n++) bfr[n] = *(const bf16x8*)(brow[n] + kk);
#pragma unroll
        for (int m = 0; m < 2; m++)
#pragma unroll
            for (int n = 0; n < 4; n++)
                acc[m][n] = __builtin_amdgcn_mfma_f32_16x16x32_bf16(af[m], bfr[n], acc[m][n], 0, 0, 0);
    }

    const int rbase = (lane >> 4) * 4;
#pragma unroll
    for (int n = 0; n < 4; n++) {
        int col = col0 + wc + n * 16 + lr;
        float b = bias[col];
#pragma unroll
        for (int m = 0; m < 2; m++) {
#pragma unroll
            for (int j = 0; j < 4; j++) {
                int row = row0 + wr + m * 16 + rbase + j;
                if (row < M) out_bf[(size_t)row * Ncols + col] = f2bf(tanhf(acc[m][n][j] + b));
            }
        }
    }
}

// ============ LDS-free MFMA K=128 single-tile, low-acc, fused epilogue ============
// Wave tile 16 rows x 128 cols (acc = 32 AGPR); block = 4 waves = 64 rows.
template<bool ABF16, bool TANH, bool L2, bool RESID, bool AUX, bool AUXBF,
         bool F32OUT, bool BF16OUT, bool BIAS>
__global__ __launch_bounds__(256)
void mfma_ep(const void* __restrict__ A_, const unsigned short* __restrict__ Wt,
             const float* __restrict__ bias, const unsigned short* __restrict__ resid_bf,
             const void* __restrict__ aux_in, float* __restrict__ aux_out,
             float* __restrict__ out, unsigned short* __restrict__ out_bf, int M)
{
    const int tid  = threadIdx.x;
    const int row0 = blockIdx.x * 64;
    const int wv   = tid >> 6, lane = tid & 63;
    const int lr   = lane & 15;
    const int lk8  = (lane >> 4) * 8;
    const int wr   = wv * 16;

    const unsigned short* Abr;
    const float*          Afr;
    {
        int r = row0 + wr + lr;
        r = r < M ? r : (M - 1);
        Abr = (const unsigned short*)A_ + ((size_t)r << 7) + lk8;
        Afr = (const float*)A_          + ((size_t)r << 7) + lk8;
    }

    f32x4 acc[8];
#pragma unroll
    for (int n = 0; n < 8; n++)
#pragma unroll
        for (int j = 0; j < 4; j++) acc[n][j] = 0.f;

#pragma unroll 2
    for (int ks = 0; ks < 4; ks++) {
        bf16x8 af, bn[8];
        if (ABF16) af = *(const bf16x8*)(Abr + ks * 32);
        else       af = ld_f32x8_as_bf(Afr + ks * 32);
#pragma unroll
        for (int n = 0; n < 8; n++)
            bn[n] = *(const bf16x8*)(Wt + (((size_t)(n * 16 + lr)) << 7) + ks * 32 + lk8);
#pragma unroll
        for (int n = 0; n < 8; n++)
            acc[n] = __builtin_amdgcn_mfma_f32_16x16x32_bf16(af, bn[n], acc[n], 0, 0, 0);
    }

    const int rbase = (lane >> 4) * 4;
    float bv[8];
#pragma unroll
    for (int n = 0; n < 8; n++) bv[n] = BIAS ? bias[n * 16 + lr] : 0.f;

#pragma unroll
    for (int j = 0; j < 4; j++) {
        int row = row0 + wr + rbase + j;
        bool ok = row < M;
        float v[8];
#pragma unroll
        for (int n = 0; n < 8; n++) {
            v[n] = acc[n][j] + bv[n];
            if (TANH) v[n] = tanhf(v[n]);
        }
        if (RESID) {
#pragma unroll
            for (int n = 0; n < 8; n++)
                if (ok) v[n] += bf2f(resid_bf[((size_t)row << 7) + n * 16 + lr]);
        }
        if (L2) {
            float s = 0.f;
#pragma unroll
            for (int n = 0; n < 8; n++) s += v[n] * v[n];
#pragma unroll
            for (int msk = 8; msk >= 1; msk >>= 1) s += __shfl_xor(s, msk);
            float sc = 1.f / fmaxf(sqrtf(s), 1e-12f);
#pragma unroll
            for (int n = 0; n < 8; n++) v[n] *= sc;
        }
        if (ok) {
#pragma unroll
            for (int n = 0; n < 8; n++) {
                size_t off = ((size_t)row << 7) + n * 16 + lr;
                if (F32OUT)  out[off] = v[n];
                if (BF16OUT) out_bf[off] = f2bf(v[n]);
                if (AUX) {
                    float ai = AUXBF ? bf2f(((const unsigned short*)aux_in)[off])
                                     : ((const float*)aux_in)[off];
                    aux_out[off] = ai + v[n];
                }
            }
        }
    }
}

// ============ scan helpers (bucket-level only, NB<=2048) ============
#define SCAN_TILE 2048

__global__ __launch_bounds__(256)
void scan_phaseA(const int* __restrict__ cnt, int* __restrict__ tilesum, int N)
{
    __shared__ int sdata[256];
    int base = blockIdx.x * SCAN_TILE + threadIdx.x * 8;
    int s = 0;
#pragma unroll
    for (int j = 0; j < 8; j++) { int i = base + j; if (i < N) s += cnt[i]; }
    sdata[threadIdx.x] = s; __syncthreads();
    for (int off = 128; off > 0; off >>= 1) {
        if (threadIdx.x < off) sdata[threadIdx.x] += sdata[threadIdx.x + off];
        __syncthreads();
    }
    if (threadIdx.x == 0) tilesum[blockIdx.x] = sdata[0];
}

__global__ void scan_phaseB(int* __restrict__ tilesum, int* __restrict__ rowptr,
                            int numTiles, int N)
{
    if (threadIdx.x == 0 && blockIdx.x == 0) {
        int run = 0;
        for (int t = 0; t < numTiles; t++) { int v = tilesum[t]; tilesum[t] = run; run += v; }
        rowptr[N] = run;
    }
}

__global__ __launch_bounds__(256)
void scan_phaseC(const int* __restrict__ cnt, const int* __restrict__ tilesum,
                 int* __restrict__ rowptr, int N)
{
    __shared__ int sdata[256];
    int base = blockIdx.x * SCAN_TILE + threadIdx.x * 8;
    int loc[8]; int s = 0;
#pragma unroll
    for (int j = 0; j < 8; j++) {
        int i = base + j; int v = (i < N) ? cnt[i] : 0;
        loc[j] = s; s += v;
    }
    sdata[threadIdx.x] = s; __syncthreads();
    int x = s;
    for (int off = 1; off < 256; off <<= 1) {
        int t = 0;
        if (threadIdx.x >= off) t = sdata[threadIdx.x - off];
        __syncthreads();
        x += t;
        sdata[threadIdx.x] = x;
        __syncthreads();
    }
    int texcl = x - s + tilesum[blockIdx.x];
#pragma unroll
    for (int j = 0; j < 8; j++) {
        int i = base + j;
        if (i < N) rowptr[i] = texcl + loc[j];
    }
}

// ============ bucketed reorder (no line-thrashing scatter) ============
#define RCHUNK 16384

__global__ __launch_bounds__(256)
void bhist_k(const int* __restrict__ rows, int* __restrict__ bcnt, int E, int NB)
{
    __shared__ int lc[1024];
    for (int b = threadIdx.x; b < NB; b += 256) lc[b] = 0;
    __syncthreads();
    int start = blockIdx.x * RCHUNK;
    int end = min(start + RCHUNK, E);
    for (int i = start + threadIdx.x; i < end; i += 256)
        atomicAdd(&lc[rows[i] >> 7], 1);
    __syncthreads();
    for (int b = threadIdx.x; b < NB; b += 256)
        if (lc[b]) atomicAdd(&bcnt[b], lc[b]);
}

__global__ void init_bcur(const int* __restrict__ bbase, int* __restrict__ bcur, int NB)
{
    int b = blockIdx.x * 256 + threadIdx.x;
    if (b < NB) bcur[b] = bbase[b];
}

// group edges by 128-row bucket; run-reserved coalesced writes; row_low in col bits 17..23
__global__ __launch_bounds__(256)
void bucket_scatter(const int* __restrict__ rows, const int* __restrict__ cols,
                    const float* __restrict__ vals, int* __restrict__ bcur,
                    int2* __restrict__ tmp, int E, int NB)
{
    __shared__ int lcnt[1024];
    __shared__ int lbase[1024];
    for (int b = threadIdx.x; b < NB; b += 256) lcnt[b] = 0;
    __syncthreads();
    int start = blockIdx.x * RCHUNK;
    int end = min(start + RCHUNK, E);
    for (int i = start + threadIdx.x; i < end; i += 256)
        atomicAdd(&lcnt[rows[i] >> 7], 1);
    __syncthreads();
    for (int b = threadIdx.x; b < NB; b += 256) {
        int c = lcnt[b];
        lbase[b] = c ? atomicAdd(&bcur[b], c) : 0;
        lcnt[b] = 0;
    }
    __syncthreads();
    for (int i = start + threadIdx.x; i < end; i += 256) {
        int r = rows[i];
        int b = r >> 7;
        int off = atomicAdd(&lcnt[b], 1);
        tmp[lbase[b] + off] = make_int2(cols[i] | ((r & 127) << 17), __float_as_int(vals[i]));
    }
}

// one block per bucket: local row-count + scan -> writes rowptr AND places edges
__global__ __launch_bounds__(256)
void csr_place(const int2* __restrict__ tmp, const int* __restrict__ bbase,
               int* __restrict__ rowptr, int2* __restrict__ packed, int M, int NB)
{
    __shared__ int lcnt[128];
    __shared__ int lofs[128];
    const int tid = threadIdx.x;
    const int b = blockIdx.x;
    const int s = bbase[b], e = bbase[b + 1];
    const int rb = b << 7;
    if (tid < 128) lcnt[tid] = 0;
    __syncthreads();
    for (int i = s + tid; i < e; i += 256)
        atomicAdd(&lcnt[(((unsigned)tmp[i].x) >> 17) & 127], 1);
    __syncthreads();
    if (tid == 0) {
        int run = s;
#pragma unroll 8
        for (int r = 0; r < 128; r++) { lofs[r] = run; run += lcnt[r]; }
    }
    __syncthreads();
    if (tid < 128 && rb + tid < M) rowptr[rb + tid] = lofs[tid];
    if (b == NB - 1 && tid == 0) rowptr[M] = e;
    if (tid < 128) lcnt[tid] = 0;
    __syncthreads();
    for (int i = s + tid; i < e; i += 256) {
        int2 t = tmp[i];
        int rl = (((unsigned)t.x) >> 17) & 127;
        int pos = lofs[rl] + atomicAdd(&lcnt[rl], 1);
        packed[pos] = make_int2(t.x & 0x1FFFF, t.y);
    }
}

// ============ CSR SpMM: 16 lanes/edge x 4 edge-groups, 16B gathers ============
__global__ __launch_bounds__(256)
void spmm_csr(const int* __restrict__ rowptr, const int2* __restrict__ packed,
              const unsigned short* __restrict__ embb, unsigned short* __restrict__ hb, int N)
{
    const int wv = threadIdx.x >> 6, lane = threadIdx.x & 63;
    const int g = lane >> 4, q = lane & 15;
    const int r = blockIdx.x * 4 + wv;
    if (r >= N) return;
    const int s = rowptr[r], e = rowptr[r + 1];
    const unsigned short* __restrict__ eb = embb + q * 8;

    float a0=0.f,a1=0.f,a2=0.f,a3=0.f,a4=0.f,a5=0.f,a6=0.f,a7=0.f;
    int i = s + g;
    for (; i + 12 < e; i += 16) {          // 4 edges per group per pass (16 in flight/wave)
#pragma unroll
        for (int u = 0; u < 4; u++) {
            int2 p = packed[i + 4 * u];
            uint4 m = *(const uint4*)(eb + ((size_t)p.x << 7));
            float v = __int_as_float(p.y);
            a0 += v * __uint_as_float(m.x << 16);
            a1 += v * __uint_as_float(m.x & 0xffff0000u);
            a2 += v * __uint_as_float(m.y << 16);
            a3 += v * __uint_as_float(m.y & 0xffff0000u);
            a4 += v * __uint_as_float(m.z << 16);
            a5 += v * __uint_as_float(m.z & 0xffff0000u);
            a6 += v * __uint_as_float(m.w << 16);
            a7 += v * __uint_as_float(m.w & 0xffff0000u);
        }
    }
    for (; i < e; i += 4) {
        int2 p = packed[i];
        uint4 m = *(const uint4*)(eb + ((size_t)p.x << 7));
        float v = __int_as_float(p.y);
        a0 += v * __uint_as_float(m.x << 16);
        a1 += v * __uint_as_float(m.x & 0xffff0000u);
        a2 += v * __uint_as_float(m.y << 16);
        a3 += v * __uint_as_float(m.y & 0xffff0000u);
        a4 += v * __uint_as_float(m.z << 16);
        a5 += v * __uint_as_float(m.z & 0xffff0000u);
        a6 += v * __uint_as_float(m.w << 16);
        a7 += v * __uint_as_float(m.w & 0xffff0000u);
    }
#pragma unroll
    for (int msk = 16; msk <= 32; msk <<= 1) {
        a0 += __shfl_xor(a0, msk); a1 += __shfl_xor(a1, msk);
        a2 += __shfl_xor(a2, msk); a3 += __shfl_xor(a3, msk);
        a4 += __shfl_xor(a4, msk); a5 += __shfl_xor(a5, msk);
        a6 += __shfl_xor(a6, msk); a7 += __shfl_xor(a7, msk);
    }
    if (g == 0) {
        unsigned o0 = (unsigned)f2bf(a0) | ((unsigned)f2bf(a1) << 16);
        unsigned o1 = (unsigned)f2bf(a2) | ((unsigned)f2bf(a3) << 16);
        unsigned o2 = (unsigned)f2bf(a4) | ((unsigned)f2bf(a5) << 16);
        unsigned o3 = (unsigned)f2bf(a6) | ((unsigned)f2bf(a7) << 16);
        *(uint4*)(hb + ((size_t)r << 7) + q * 8) = make_uint4(o0, o1, o2, o3);
    }
}

// ============ launch ============
extern "C" void kernel_launch(void* const* d_in, const int* in_sizes, int n_in,
                              void* d_out, int out_size, void* d_ws, size_t ws_size,
                              hipStream_t stream)
{
    const float* feat  = (const float*)d_in[0];
    const int*   srows = (const int*)  d_in[1];
    const int*   scols = (const int*)  d_in[2];
    const float* svals = (const float*)d_in[3];
    const float* Wf0   = (const float*)d_in[4];
    const float* bf0   = (const float*)d_in[5];
    const float* Wf1   = (const float*)d_in[6];
    const float* bf1   = (const float*)d_in[7];
    const float* Wg    = (const float*)d_in[8];
    const float* Wemb  = (const float*)d_in[9];
    const float* bemb  = (const float*)d_in[10];
    const float* Wl    = (const float*)d_in[11];
    const float* bl    = (const float*)d_in[12];
    const float* Wr    = (const float*)d_in[13];
    const float* br    = (const float*)d_in[14];

    const int M = in_sizes[0] / 512;   // 100000 nodes
    const int E = in_sizes[1];         // 3200000 edges
    const int NB = (M + 127) >> 7;     // 782 buckets

    float* out = (float*)d_out;
    float* R0 = out;                        // emb final
    float* R1 = out + (size_t)M * 128;      // lft final
    float* R2 = out + (size_t)M * 256;      // rgt final

    // ---- ws layout ----
    float* ws = (float*)d_ws;
    float* accf = ws;                                      // [M,128] f32 gnn_acc; tmp aliases
    int2*  tmp  = (int2*)ws;                               // [E] int2, dead before s4
    int*   ip = (int*)(ws + (size_t)M * 128);
    int*   rowptr  = ip;                                   // M+1
    int2*  packed  = (int2*)(ip + (((size_t)M + 4) & ~(size_t)3));  // E
    int*   tilesum = (int*)(packed + E);                   // 64
    int*   bcnt    = tilesum + 64;                         // NB
    int*   bbase   = bcnt + 1024;                          // NB+1
    int*   bcur    = bbase + 1032;                         // NB
    unsigned short* Wt0   = (unsigned short*)(bcur + 1024);    // [256][512]
    unsigned short* Wt1   = Wt0 + 256 * 512;                   // [128][256]
    unsigned short* Wg0t  = Wt1 + 128 * 256;                   // 7x [128][128]
    unsigned short* Wg1t  = Wg0t + 16384;
    unsigned short* Wembt = Wg1t + 16384;
    unsigned short* Wl0t  = Wembt + 16384;
    unsigned short* Wl1t  = Wl0t + 16384;
    unsigned short* Wr0t  = Wl1t + 16384;
    unsigned short* Wr1t  = Wr0t + 16384;

    // ---- d_out scratch timeline ----
    unsigned short* R0a = (unsigned short*)R0;
    unsigned short* R0b = (unsigned short*)R0 + (size_t)M * 128;
    unsigned short* R1a = (unsigned short*)R1;
    unsigned short* feat_bf = (unsigned short*)R0;  // [M,512] = R0+R1, dead after s1
    unsigned short* x1_bf   = (unsigned short*)R2;  // [M,256], dead after s2
    unsigned short* x_bf    = R0a;                  // s2 out; spmm3 src; s4 aux (feat_bf dead)
    unsigned short* h_bf    = R0b;                  // spmm3->s4 ; spmm5->s6
    unsigned short* n0_bf   = R1a;                  // s4 -> spmm5
    unsigned short* n1_bf   = R0a;                  // s6 -> s10/s8 (x_bf dead)
    unsigned short* rgt0_bf = R1a;                  // s10 -> s11 (n0 dead)
    unsigned short* lft0_bf = R0b;                  // s8 -> s9 (h dead)

    dim3 blk(256);
    const int gm64 = (M + 63) / 64;                 // 1563
    const int nch  = (E + RCHUNK - 1) / RCHUNK;

    // weight converts
    wconv<<<(512*256 + 255)/256, blk, 0, stream>>>(Wf0, Wt0, 512, 256);
    wconv<<<(256*128 + 255)/256, blk, 0, stream>>>(Wf1, Wt1, 256, 128);
    wconv<<<64, blk, 0, stream>>>(Wg,          Wg0t,  128, 128);
    wconv<<<64, blk, 0, stream>>>(Wg + 16384,  Wg1t,  128, 128);
    wconv<<<64, blk, 0, stream>>>(Wemb,        Wembt, 128, 128);
    wconv<<<64, blk, 0, stream>>>(Wl,          Wl0t,  128, 128);
    wconv<<<64, blk, 0, stream>>>(Wl + 16384,  Wl1t,  128, 128);
    wconv<<<64, blk, 0, stream>>>(Wr,          Wr0t,  128, 128);
    wconv<<<64, blk, 0, stream>>>(Wr + 16384,  Wr1t,  128, 128);

    // feat -> bf16 (into R0+R1; streams at HBM BW)
    f32_to_bf16<<<(int)(((long)M * 64 + 255) / 256), blk, 0, stream>>>(feat, feat_bf, (long)M * 64);

    // ---- CSR build: bucket pass + fused rowptr/place ----
    hipMemsetAsync(bcnt, 0, (size_t)NB * 4, stream);
    bhist_k<<<nch, blk, 0, stream>>>(srows, bcnt, E, NB);
    scan_phaseA<<<1, blk, 0, stream>>>(bcnt, tilesum, NB);
    scan_phaseB<<<1, 64, 0, stream>>>(tilesum, bbase, 1, NB);
    scan_phaseC<<<1, blk, 0, stream>>>(bcnt, tilesum, bbase, NB);
    init_bcur<<<(NB + 255)/256, blk, 0, stream>>>(bbase, bcur, NB);
    bucket_scatter<<<nch, blk, 0, stream>>>(srows, scols, svals, bcur, tmp, E, NB);
    csr_place<<<NB, blk, 0, stream>>>(tmp, bbase, rowptr, packed, M, NB);

    // ---- network ----
    // s1: x1_bf = tanh(feat @ Wf0 + bf0)
    mfma_direct<<<dim3(gm64,2),blk,0,stream>>>(feat_bf, Wt0, bf0, x1_bf, M, 512, 256);
    // s2: x_bf = tanh(x1 @ Wf1 + bf1)
    mfma_direct<<<dim3(gm64,1),blk,0,stream>>>(x1_bf, Wt1, bf1, x_bf, M, 256, 128);
    // spmm3: h_bf = S @ x
    spmm_csr<<<(M + 3) / 4, blk, 0, stream>>>(rowptr, packed, x_bf, h_bf, M);
    // s4: n0 = l2norm(tanh(h @ Wg0)) -> n0_bf; accf = x + n0
    mfma_ep<true,true,true,false,true,true,false,true,false><<<gm64,blk,0,stream>>>(
        h_bf, Wg0t, nullptr, nullptr, x_bf, accf, nullptr, n0_bf, M);
    // spmm5: h_bf = S @ n0
    spmm_csr<<<(M + 3) / 4, blk, 0, stream>>>(rowptr, packed, n0_bf, h_bf, M);
    // s6: n1 = l2norm(tanh(h @ Wg1)) -> n1_bf; accf += n1 (in-place)
    mfma_ep<true,true,true,false,true,false,false,true,false><<<gm64,blk,0,stream>>>(
        h_bf, Wg1t, nullptr, nullptr, accf, accf, nullptr, n1_bf, M);
    // s10: rgt0 = tanh(n1 @ Wr0 + br0) + n1 -> rgt0_bf
    mfma_ep<true,true,false,true,false,false,false,true,true><<<gm64,blk,0,stream>>>(
        n1_bf, Wr0t, br, n1_bf, nullptr, nullptr, nullptr, rgt0_bf, M);
    // s11: rgt = tanh(rgt0 @ Wr1 + br1) -> R2 final
    mfma_ep<true,true,false,false,false,false,true,false,true><<<gm64,blk,0,stream>>>(
        rgt0_bf, Wr1t, br + 128, nullptr, nullptr, nullptr, R2, nullptr, M);
    // s8: lft0 = tanh(n1 @ Wl0 + bl0) + n1 -> lft0_bf
    mfma_ep<true,true,false,true,false,false,false,true,true><<<gm64,blk,0,stream>>>(
        n1_bf, Wl0t, bl, n1_bf, nullptr, nullptr, nullptr, lft0_bf, M);
    // s9: lft = tanh(lft0 @ Wl1 + bl1) -> R1 final
    mfma_ep<true,true,false,false,false,false,true,false,true><<<gm64,blk,0,stream>>>(
        lft0_bf, Wl1t, bl + 128, nullptr, nullptr, nullptr, R1, nullptr, M);
    // s7: emb = l2norm(accf @ Wemb + bemb) -> R0 final (last: frees R0 scratch)
    mfma_ep<false,false,true,false,false,false,true,false,true><<<gm64,blk,0,stream>>>(
        accf, Wembt, bemb, nullptr, nullptr, nullptr, R0, nullptr, M);
}

// Round 12
// 905.234 us; speedup vs baseline: 1.0402x; 1.0402x over previous
//
#include <hip/hip_runtime.h>
#include <math.h>

typedef short bf16x8 __attribute__((ext_vector_type(8)));
typedef float f32x4  __attribute__((ext_vector_type(4)));

__device__ __forceinline__ unsigned short f2bf(float x) {
    unsigned u = __float_as_uint(x);
    unsigned r = u + 0x7FFFu + ((u >> 16) & 1u);   // RNE
    return (unsigned short)(r >> 16);
}
__device__ __forceinline__ float bf2f(unsigned short b) {
    return __uint_as_float(((unsigned)b) << 16);
}
__device__ __forceinline__ bf16x8 ld_f32x8_as_bf(const float* p) {
    float4 a = *(const float4*)p;
    float4 b = *(const float4*)(p + 4);
    bf16x8 v;
    v[0] = (short)f2bf(a.x); v[1] = (short)f2bf(a.y);
    v[2] = (short)f2bf(a.z); v[3] = (short)f2bf(a.w);
    v[4] = (short)f2bf(b.x); v[5] = (short)f2bf(b.y);
    v[6] = (short)f2bf(b.z); v[7] = (short)f2bf(b.w);
    return v;
}

// ============ weight convert+transpose with epilogue-coalescing row permutation ============
// PERM=1 (mfma_direct): within each 64-col group, store logical col c at row (c&3)*16+(c>>2)
//   -> fragment slot n @ lane lr holds logical col 4*lr+n  (contiguous per lane)
// PERM=2 (mfma_ep): within each 128-col group, store logical col c at row (c&7)*16+(c>>3)
//   -> fragment slot n @ lane lr holds logical col 8*lr+n
template<int PERM>
__global__ __launch_bounds__(256)
void wconv(const float* __restrict__ W, unsigned short* __restrict__ Wt, int K, int N)
{
    int id = blockIdx.x * 256 + threadIdx.x;
    if (id >= K * N) return;
    int c = id / K, k = id - c * K;
    int p;
    if (PERM == 1) {
        int hi = c & ~63, c64 = c & 63;
        p = hi + ((c64 & 3) << 4) + (c64 >> 2);
    } else if (PERM == 2) {
        int hi = c & ~127, c7 = c & 127;
        p = hi + ((c7 & 7) << 4) + (c7 >> 3);
    } else p = c;
    Wt[(size_t)p * K + k] = f2bf(W[(size_t)k * N + c]);
}

// ============ bulk f32 -> bf16 (for feat; streams at HBM BW) ============
__global__ __launch_bounds__(256)
void f32_to_bf16(const float* __restrict__ in, unsigned short* __restrict__ outb, long n8)
{
    long id = (long)blockIdx.x * 256 + threadIdx.x;   // one per 8 elems
    if (id >= n8) return;
    const float4* p = (const float4*)(in + id * 8);
    float4 a = p[0], b = p[1];
    *(ushort4*)(outb + id * 8)     = make_ushort4(f2bf(a.x), f2bf(a.y), f2bf(a.z), f2bf(a.w));
    *(ushort4*)(outb + id * 8 + 4) = make_ushort4(f2bf(b.x), f2bf(b.y), f2bf(b.z), f2bf(b.w));
}

// ============ LDS-free MFMA GEMM (R10 shape) + coalesced permuted epilogue ============
// A bf16 [M,K]; Wt bf16 PERM=1 [Ncols][K]. Wave tile 64x64; block 128x128.
// Lane lr slot n = logical col wc+4*lr+n -> one ushort4 store per (m,j).
__global__ __launch_bounds__(256)
void mfma_direct(const unsigned short* __restrict__ Ab, const unsigned short* __restrict__ Wt,
                 const float* __restrict__ bias, unsigned short* __restrict__ out_bf,
                 int M, int K, int Ncols)
{
    const int tid  = threadIdx.x;
    const int row0 = blockIdx.x * 128;
    const int col0 = blockIdx.y * 128;
    const int wv   = tid >> 6, lane = tid & 63;
    const int wr   = (wv >> 1) * 64, wc = (wv & 1) * 64;
    const int lr   = lane & 15;
    const int lk8  = (lane >> 4) * 8;

    const unsigned short* arow[4];
    const unsigned short* brow[4];
#pragma unroll
    for (int m = 0; m < 4; m++) {
        int r = row0 + wr + m * 16 + lr;
        r = r < M ? r : (M - 1);
        arow[m] = Ab + (size_t)r * K + lk8;
    }
#pragma unroll
    for (int n = 0; n < 4; n++)
        brow[n] = Wt + (size_t)(col0 + wc + n * 16 + lr) * K + lk8;

    f32x4 acc[4][4];
#pragma unroll
    for (int m = 0; m < 4; m++)
#pragma unroll
        for (int n = 0; n < 4; n++)
#pragma unroll
            for (int j = 0; j < 4; j++) acc[m][n][j] = 0.f;

#pragma unroll 2
    for (int kk = 0; kk < K; kk += 32) {
        bf16x8 af[4], bfr[4];
#pragma unroll
        for (int m = 0; m < 4; m++) af[m]  = *(const bf16x8*)(arow[m] + kk);
#pragma unroll
        for (int n = 0; n < 4; n++) bfr[n] = *(const bf16x8*)(brow[n] + kk);
#pragma unroll
        for (int m = 0; m < 4; m++)
#pragma unroll
            for (int n = 0; n < 4; n++)
                acc[m][n] = __builtin_amdgcn_mfma_f32_16x16x32_bf16(af[m], bfr[n], acc[m][n], 0, 0, 0);
    }

    // epilogue: lane lr covers cols col0+wc+4*lr .. +3 (contiguous)
    const int cbase = col0 + wc + lr * 4;
    float4 b4 = *(const float4*)(bias + cbase);
    float bv[4] = {b4.x, b4.y, b4.z, b4.w};
    const int rbase = (lane >> 4) * 4;
#pragma unroll
    for (int m = 0; m < 4; m++) {
#pragma unroll
        for (int j = 0; j < 4; j++) {
            int row = row0 + wr + m * 16 + rbase + j;
            if (row < M) {
                ushort4 o;
                o.x = f2bf(tanhf(acc[m][0][j] + bv[0]));
                o.y = f2bf(tanhf(acc[m][1][j] + bv[1]));
                o.z = f2bf(tanhf(acc[m][2][j] + bv[2]));
                o.w = f2bf(tanhf(acc[m][3][j] + bv[3]));
                *(ushort4*)(out_bf + (size_t)row * Ncols + cbase) = o;
            }
        }
    }
}

// ============ LDS-free MFMA K=128 (R11 shape) + coalesced permuted epilogue ============
// Wave tile 16 rows x 128 cols; block 64 rows. Wt PERM=2: lane lr slot n = col 8*lr+n.
template<bool ABF16, bool TANH, bool L2, bool RESID, bool AUX, bool AUXBF,
         bool F32OUT, bool BF16OUT, bool BIAS>
__global__ __launch_bounds__(256)
void mfma_ep(const void* __restrict__ A_, const unsigned short* __restrict__ Wt,
             const float* __restrict__ bias, const unsigned short* __restrict__ resid_bf,
             const void* __restrict__ aux_in, float* __restrict__ aux_out,
             float* __restrict__ out, unsigned short* __restrict__ out_bf, int M)
{
    const int tid  = threadIdx.x;
    const int row0 = blockIdx.x * 64;
    const int wv   = tid >> 6, lane = tid & 63;
    const int lr   = lane & 15;
    const int lk8  = (lane >> 4) * 8;
    const int wr   = wv * 16;

    const unsigned short* Abr;
    const float*          Afr;
    {
        int r = row0 + wr + lr;
        r = r < M ? r : (M - 1);
        Abr = (const unsigned short*)A_ + ((size_t)r << 7) + lk8;
        Afr = (const float*)A_          + ((size_t)r << 7) + lk8;
    }

    f32x4 acc[8];
#pragma unroll
    for (int n = 0; n < 8; n++)
#pragma unroll
        for (int j = 0; j < 4; j++) acc[n][j] = 0.f;

#pragma unroll 2
    for (int ks = 0; ks < 4; ks++) {
        bf16x8 af, bn[8];
        if (ABF16) af = *(const bf16x8*)(Abr + ks * 32);
        else       af = ld_f32x8_as_bf(Afr + ks * 32);
#pragma unroll
        for (int n = 0; n < 8; n++)
            bn[n] = *(const bf16x8*)(Wt + (((size_t)(n * 16 + lr)) << 7) + ks * 32 + lk8);
#pragma unroll
        for (int n = 0; n < 8; n++)
            acc[n] = __builtin_amdgcn_mfma_f32_16x16x32_bf16(af, bn[n], acc[n], 0, 0, 0);
    }

    // lane lr covers cols 8*lr .. 8*lr+7 (contiguous)
    const int cbase = lr * 8;
    float bv[8];
    if (BIAS) {
        float4 b0 = *(const float4*)(bias + cbase);
        float4 b1 = *(const float4*)(bias + cbase + 4);
        bv[0]=b0.x; bv[1]=b0.y; bv[2]=b0.z; bv[3]=b0.w;
        bv[4]=b1.x; bv[5]=b1.y; bv[6]=b1.z; bv[7]=b1.w;
    } else {
#pragma unroll
        for (int n = 0; n < 8; n++) bv[n] = 0.f;
    }
    const int rbase = (lane >> 4) * 4;

#pragma unroll
    for (int j = 0; j < 4; j++) {
        int row = row0 + wr + rbase + j;
        bool ok = row < M;
        size_t base = ((size_t)row << 7) + cbase;
        float v[8];
#pragma unroll
        for (int n = 0; n < 8; n++) {
            v[n] = acc[n][j] + bv[n];
            if (TANH) v[n] = tanhf(v[n]);
        }
        if (RESID) {
            if (ok) {
                bf16x8 rv = *(const bf16x8*)(resid_bf + base);
#pragma unroll
                for (int n = 0; n < 8; n++) v[n] += bf2f((unsigned short)rv[n]);
            }
        }
        if (L2) {
            float s = 0.f;
#pragma unroll
            for (int n = 0; n < 8; n++) s += v[n] * v[n];
#pragma unroll
            for (int msk = 8; msk >= 1; msk >>= 1) s += __shfl_xor(s, msk);
            float sc = 1.f / fmaxf(sqrtf(s), 1e-12f);
#pragma unroll
            for (int n = 0; n < 8; n++) v[n] *= sc;
        }
        if (ok) {
            if (F32OUT) {
                *(float4*)(out + base)     = make_float4(v[0], v[1], v[2], v[3]);
                *(float4*)(out + base + 4) = make_float4(v[4], v[5], v[6], v[7]);
            }
            if (BF16OUT) {
                bf16x8 o;
#pragma unroll
                for (int n = 0; n < 8; n++) o[n] = (short)f2bf(v[n]);
                *(bf16x8*)(out_bf + base) = o;
            }
            if (AUX) {
                float ai[8];
                if (AUXBF) {
                    bf16x8 av = *(const bf16x8*)((const unsigned short*)aux_in + base);
#pragma unroll
                    for (int n = 0; n < 8; n++) ai[n] = bf2f((unsigned short)av[n]);
                } else {
                    float4 a0 = *(const float4*)((const float*)aux_in + base);
                    float4 a1 = *(const float4*)((const float*)aux_in + base + 4);
                    ai[0]=a0.x; ai[1]=a0.y; ai[2]=a0.z; ai[3]=a0.w;
                    ai[4]=a1.x; ai[5]=a1.y; ai[6]=a1.z; ai[7]=a1.w;
                }
                *(float4*)(aux_out + base)     = make_float4(ai[0]+v[0], ai[1]+v[1], ai[2]+v[2], ai[3]+v[3]);
                *(float4*)(aux_out + base + 4) = make_float4(ai[4]+v[4], ai[5]+v[5], ai[6]+v[6], ai[7]+v[7]);
            }
        }
    }
}

// ============ scan helpers (bucket-level only, NB<=2048) ============
#define SCAN_TILE 2048

__global__ __launch_bounds__(256)
void scan_phaseA(const int* __restrict__ cnt, int* __restrict__ tilesum, int N)
{
    __shared__ int sdata[256];
    int base = blockIdx.x * SCAN_TILE + threadIdx.x * 8;
    int s = 0;
#pragma unroll
    for (int j = 0; j < 8; j++) { int i = base + j; if (i < N) s += cnt[i]; }
    sdata[threadIdx.x] = s; __syncthreads();
    for (int off = 128; off > 0; off >>= 1) {
        if (threadIdx.x < off) sdata[threadIdx.x] += sdata[threadIdx.x + off];
        __syncthreads();
    }
    if (threadIdx.x == 0) tilesum[blockIdx.x] = sdata[0];
}

__global__ void scan_phaseB(int* __restrict__ tilesum, int* __restrict__ rowptr,
                            int numTiles, int N)
{
    if (threadIdx.x == 0 && blockIdx.x == 0) {
        int run = 0;
        for (int t = 0; t < numTiles; t++) { int v = tilesum[t]; tilesum[t] = run; run += v; }
        rowptr[N] = run;
    }
}

__global__ __launch_bounds__(256)
void scan_phaseC(const int* __restrict__ cnt, const int* __restrict__ tilesum,
                 int* __restrict__ rowptr, int N)
{
    __shared__ int sdata[256];
    int base = blockIdx.x * SCAN_TILE + threadIdx.x * 8;
    int loc[8]; int s = 0;
#pragma unroll
    for (int j = 0; j < 8; j++) {
        int i = base + j; int v = (i < N) ? cnt[i] : 0;
        loc[j] = s; s += v;
    }
    sdata[threadIdx.x] = s; __syncthreads();
    int x = s;
    for (int off = 1; off < 256; off <<= 1) {
        int t = 0;
        if (threadIdx.x >= off) t = sdata[threadIdx.x - off];
        __syncthreads();
        x += t;
        sdata[threadIdx.x] = x;
        __syncthreads();
    }
    int texcl = x - s + tilesum[blockIdx.x];
#pragma unroll
    for (int j = 0; j < 8; j++) {
        int i = base + j;
        if (i < N) rowptr[i] = texcl + loc[j];
    }
}

// ============ bucketed reorder (no line-thrashing scatter) ============
#define RCHUNK 16384

__global__ __launch_bounds__(256)
void bhist_k(const int* __restrict__ rows, int* __restrict__ bcnt, int E, int NB)
{
    __shared__ int lc[1024];
    for (int b = threadIdx.x; b < NB; b += 256) lc[b] = 0;
    __syncthreads();
    int start = blockIdx.x * RCHUNK;
    int end = min(start + RCHUNK, E);
    for (int i = start + threadIdx.x; i < end; i += 256)
        atomicAdd(&lc[rows[i] >> 7], 1);
    __syncthreads();
    for (int b = threadIdx.x; b < NB; b += 256)
        if (lc[b]) atomicAdd(&bcnt[b], lc[b]);
}

__global__ void init_bcur(const int* __restrict__ bbase, int* __restrict__ bcur, int NB)
{
    int b = blockIdx.x * 256 + threadIdx.x;
    if (b < NB) bcur[b] = bbase[b];
}

__global__ __launch_bounds__(256)
void bucket_scatter(const int* __restrict__ rows, const int* __restrict__ cols,
                    const float* __restrict__ vals, int* __restrict__ bcur,
                    int2* __restrict__ tmp, int E, int NB)
{
    __shared__ int lcnt[1024];
    __shared__ int lbase[1024];
    for (int b = threadIdx.x; b < NB; b += 256) lcnt[b] = 0;
    __syncthreads();
    int start = blockIdx.x * RCHUNK;
    int end = min(start + RCHUNK, E);
    for (int i = start + threadIdx.x; i < end; i += 256)
        atomicAdd(&lcnt[rows[i] >> 7], 1);
    __syncthreads();
    for (int b = threadIdx.x; b < NB; b += 256) {
        int c = lcnt[b];
        lbase[b] = c ? atomicAdd(&bcur[b], c) : 0;
        lcnt[b] = 0;
    }
    __syncthreads();
    for (int i = start + threadIdx.x; i < end; i += 256) {
        int r = rows[i];
        int b = r >> 7;
        int off = atomicAdd(&lcnt[b], 1);
        tmp[lbase[b] + off] = make_int2(cols[i] | ((r & 127) << 17), __float_as_int(vals[i]));
    }
}

__global__ __launch_bounds__(256)
void csr_place(const int2* __restrict__ tmp, const int* __restrict__ bbase,
               int* __restrict__ rowptr, int2* __restrict__ packed, int M, int NB)
{
    __shared__ int lcnt[128];
    __shared__ int lofs[128];
    const int tid = threadIdx.x;
    const int b = blockIdx.x;
    const int s = bbase[b], e = bbase[b + 1];
    const int rb = b << 7;
    if (tid < 128) lcnt[tid] = 0;
    __syncthreads();
    for (int i = s + tid; i < e; i += 256)
        atomicAdd(&lcnt[(((unsigned)tmp[i].x) >> 17) & 127], 1);
    __syncthreads();
    if (tid == 0) {
        int run = s;
#pragma unroll 8
        for (int r = 0; r < 128; r++) { lofs[r] = run; run += lcnt[r]; }
    }
    __syncthreads();
    if (tid < 128 && rb + tid < M) rowptr[rb + tid] = lofs[tid];
    if (b == NB - 1 && tid == 0) rowptr[M] = e;
    if (tid < 128) lcnt[tid] = 0;
    __syncthreads();
    for (int i = s + tid; i < e; i += 256) {
        int2 t = tmp[i];
        int rl = (((unsigned)t.x) >> 17) & 127;
        int pos = lofs[rl] + atomicAdd(&lcnt[rl], 1);
        packed[pos] = make_int2(t.x & 0x1FFFF, t.y);
    }
}

// ============ CSR SpMM: 16 lanes/edge x 4 edge-groups, 16B gathers ============
__global__ __launch_bounds__(256)
void spmm_csr(const int* __restrict__ rowptr, const int2* __restrict__ packed,
              const unsigned short* __restrict__ embb, unsigned short* __restrict__ hb, int N)
{
    const int wv = threadIdx.x >> 6, lane = threadIdx.x & 63;
    const int g = lane >> 4, q = lane & 15;
    const int r = blockIdx.x * 4 + wv;
    if (r >= N) return;
    const int s = rowptr[r], e = rowptr[r + 1];
    const unsigned short* __restrict__ eb = embb + q * 8;

    float a0=0.f,a1=0.f,a2=0.f,a3=0.f,a4=0.f,a5=0.f,a6=0.f,a7=0.f;
    int i = s + g;
    for (; i + 12 < e; i += 16) {
#pragma unroll
        for (int u = 0; u < 4; u++) {
            int2 p = packed[i + 4 * u];
            uint4 m = *(const uint4*)(eb + ((size_t)p.x << 7));
            float v = __int_as_float(p.y);
            a0 += v * __uint_as_float(m.x << 16);
            a1 += v * __uint_as_float(m.x & 0xffff0000u);
            a2 += v * __uint_as_float(m.y << 16);
            a3 += v * __uint_as_float(m.y & 0xffff0000u);
            a4 += v * __uint_as_float(m.z << 16);
            a5 += v * __uint_as_float(m.z & 0xffff0000u);
            a6 += v * __uint_as_float(m.w << 16);
            a7 += v * __uint_as_float(m.w & 0xffff0000u);
        }
    }
    for (; i < e; i += 4) {
        int2 p = packed[i];
        uint4 m = *(const uint4*)(eb + ((size_t)p.x << 7));
        float v = __int_as_float(p.y);
        a0 += v * __uint_as_float(m.x << 16);
        a1 += v * __uint_as_float(m.x & 0xffff0000u);
        a2 += v * __uint_as_float(m.y << 16);
        a3 += v * __uint_as_float(m.y & 0xffff0000u);
        a4 += v * __uint_as_float(m.z << 16);
        a5 += v * __uint_as_float(m.z & 0xffff0000u);
        a6 += v * __uint_as_float(m.w << 16);
        a7 += v * __uint_as_float(m.w & 0xffff0000u);
    }
#pragma unroll
    for (int msk = 16; msk <= 32; msk <<= 1) {
        a0 += __shfl_xor(a0, msk); a1 += __shfl_xor(a1, msk);
        a2 += __shfl_xor(a2, msk); a3 += __shfl_xor(a3, msk);
        a4 += __shfl_xor(a4, msk); a5 += __shfl_xor(a5, msk);
        a6 += __shfl_xor(a6, msk); a7 += __shfl_xor(a7, msk);
    }
    if (g == 0) {
        unsigned o0 = (unsigned)f2bf(a0) | ((unsigned)f2bf(a1) << 16);
        unsigned o1 = (unsigned)f2bf(a2) | ((unsigned)f2bf(a3) << 16);
        unsigned o2 = (unsigned)f2bf(a4) | ((unsigned)f2bf(a5) << 16);
        unsigned o3 = (unsigned)f2bf(a6) | ((unsigned)f2bf(a7) << 16);
        *(uint4*)(hb + ((size_t)r << 7) + q * 8) = make_uint4(o0, o1, o2, o3);
    }
}

// ============ launch ============
extern "C" void kernel_launch(void* const* d_in, const int* in_sizes, int n_in,
                              void* d_out, int out_size, void* d_ws, size_t ws_size,
                              hipStream_t stream)
{
    const float* feat  = (const float*)d_in[0];
    const int*   srows = (const int*)  d_in[1];
    const int*   scols = (const int*)  d_in[2];
    const float* svals = (const float*)d_in[3];
    const float* Wf0   = (const float*)d_in[4];
    const float* bf0   = (const float*)d_in[5];
    const float* Wf1   = (const float*)d_in[6];
    const float* bf1   = (const float*)d_in[7];
    const float* Wg    = (const float*)d_in[8];
    const float* Wemb  = (const float*)d_in[9];
    const float* bemb  = (const float*)d_in[10];
    const float* Wl    = (const float*)d_in[11];
    const float* bl    = (const float*)d_in[12];
    const float* Wr    = (const float*)d_in[13];
    const float* br    = (const float*)d_in[14];

    const int M = in_sizes[0] / 512;   // 100000 nodes
    const int E = in_sizes[1];         // 3200000 edges
    const int NB = (M + 127) >> 7;     // 782 buckets

    float* out = (float*)d_out;
    float* R0 = out;                        // emb final
    float* R1 = out + (size_t)M * 128;      // lft final
    float* R2 = out + (size_t)M * 256;      // rgt final

    // ---- ws layout ----
    float* ws = (float*)d_ws;
    float* accf = ws;                                      // [M,128] f32 gnn_acc; tmp aliases
    int2*  tmp  = (int2*)ws;                               // [E] int2, dead before s4
    int*   ip = (int*)(ws + (size_t)M * 128);
    int*   rowptr  = ip;                                   // M+1
    int2*  packed  = (int2*)(ip + (((size_t)M + 4) & ~(size_t)3));  // E
    int*   tilesum = (int*)(packed + E);                   // 64
    int*   bcnt    = tilesum + 64;                         // NB
    int*   bbase   = bcnt + 1024;                          // NB+1
    int*   bcur    = bbase + 1032;                         // NB
    unsigned short* Wt0   = (unsigned short*)(bcur + 1024);    // [256][512]
    unsigned short* Wt1   = Wt0 + 256 * 512;                   // [128][256]
    unsigned short* Wg0t  = Wt1 + 128 * 256;                   // 7x [128][128]
    unsigned short* Wg1t  = Wg0t + 16384;
    unsigned short* Wembt = Wg1t + 16384;
    unsigned short* Wl0t  = Wembt + 16384;
    unsigned short* Wl1t  = Wl0t + 16384;
    unsigned short* Wr0t  = Wl1t + 16384;
    unsigned short* Wr1t  = Wr0t + 16384;

    // ---- d_out scratch timeline ----
    unsigned short* R0a = (unsigned short*)R0;
    unsigned short* R0b = (unsigned short*)R0 + (size_t)M * 128;
    unsigned short* R1a = (unsigned short*)R1;
    unsigned short* feat_bf = (unsigned short*)R0;  // [M,512] = R0+R1, dead after s1
    unsigned short* x1_bf   = (unsigned short*)R2;  // [M,256], dead after s2
    unsigned short* x_bf    = R0a;                  // s2 out; spmm3 src; s4 aux (feat_bf dead)
    unsigned short* h_bf    = R0b;                  // spmm3->s4 ; spmm5->s6
    unsigned short* n0_bf   = R1a;                  // s4 -> spmm5
    unsigned short* n1_bf   = R0a;                  // s6 -> s10/s8 (x_bf dead)
    unsigned short* rgt0_bf = R1a;                  // s10 -> s11 (n0 dead)
    unsigned short* lft0_bf = R0b;                  // s8 -> s9 (h dead)

    dim3 blk(256);
    const int gm128 = (M + 127) / 128;
    const int gm64  = (M + 63) / 64;
    const int nch   = (E + RCHUNK - 1) / RCHUNK;

    // weight converts (PERM=1 for mfma_direct weights, PERM=2 for mfma_ep weights)
    wconv<1><<<(512*256 + 255)/256, blk, 0, stream>>>(Wf0, Wt0, 512, 256);
    wconv<1><<<(256*128 + 255)/256, blk, 0, stream>>>(Wf1, Wt1, 256, 128);
    wconv<2><<<64, blk, 0, stream>>>(Wg,          Wg0t,  128, 128);
    wconv<2><<<64, blk, 0, stream>>>(Wg + 16384,  Wg1t,  128, 128);
    wconv<2><<<64, blk, 0, stream>>>(Wemb,        Wembt, 128, 128);
    wconv<2><<<64, blk, 0, stream>>>(Wl,          Wl0t,  128, 128);
    wconv<2><<<64, blk, 0, stream>>>(Wl + 16384,  Wl1t,  128, 128);
    wconv<2><<<64, blk, 0, stream>>>(Wr,          Wr0t,  128, 128);
    wconv<2><<<64, blk, 0, stream>>>(Wr + 16384,  Wr1t,  128, 128);

    // feat -> bf16 (into R0+R1; streams at HBM BW)
    f32_to_bf16<<<(int)(((long)M * 64 + 255) / 256), blk, 0, stream>>>(feat, feat_bf, (long)M * 64);

    // ---- CSR build: bucket pass + fused rowptr/place ----
    hipMemsetAsync(bcnt, 0, (size_t)NB * 4, stream);
    bhist_k<<<nch, blk, 0, stream>>>(srows, bcnt, E, NB);
    scan_phaseA<<<1, blk, 0, stream>>>(bcnt, tilesum, NB);
    scan_phaseB<<<1, 64, 0, stream>>>(tilesum, bbase, 1, NB);
    scan_phaseC<<<1, blk, 0, stream>>>(bcnt, tilesum, bbase, NB);
    init_bcur<<<(NB + 255)/256, blk, 0, stream>>>(bbase, bcur, NB);
    bucket_scatter<<<nch, blk, 0, stream>>>(srows, scols, svals, bcur, tmp, E, NB);
    csr_place<<<NB, blk, 0, stream>>>(tmp, bbase, rowptr, packed, M, NB);

    // ---- network ----
    // s1: x1_bf = tanh(feat @ Wf0 + bf0)
    mfma_direct<<<dim3(gm128,2),blk,0,stream>>>(feat_bf, Wt0, bf0, x1_bf, M, 512, 256);
    // s2: x_bf = tanh(x1 @ Wf1 + bf1)
    mfma_direct<<<dim3(gm128,1),blk,0,stream>>>(x1_bf, Wt1, bf1, x_bf, M, 256, 128);
    // spmm3: h_bf = S @ x
    spmm_csr<<<(M + 3) / 4, blk, 0, stream>>>(rowptr, packed, x_bf, h_bf, M);
    // s4: n0 = l2norm(tanh(h @ Wg0)) -> n0_bf; accf = x + n0
    mfma_ep<true,true,true,false,true,true,false,true,false><<<gm64,blk,0,stream>>>(
        h_bf, Wg0t, nullptr, nullptr, x_bf, accf, nullptr, n0_bf, M);
    // spmm5: h_bf = S @ n0
    spmm_csr<<<(M + 3) / 4, blk, 0, stream>>>(rowptr, packed, n0_bf, h_bf, M);
    // s6: n1 = l2norm(tanh(h @ Wg1)) -> n1_bf; accf += n1 (in-place)
    mfma_ep<true,true,true,false,true,false,false,true,false><<<gm64,blk,0,stream>>>(
        h_bf, Wg1t, nullptr, nullptr, accf, accf, nullptr, n1_bf, M);
    // s10: rgt0 = tanh(n1 @ Wr0 + br0) + n1 -> rgt0_bf
    mfma_ep<true,true,false,true,false,false,false,true,true><<<gm64,blk,0,stream>>>(
        n1_bf, Wr0t, br, n1_bf, nullptr, nullptr, nullptr, rgt0_bf, M);
    // s11: rgt = tanh(rgt0 @ Wr1 + br1) -> R2 final
    mfma_ep<true,true,false,false,false,false,true,false,true><<<gm64,blk,0,stream>>>(
        rgt0_bf, Wr1t, br + 128, nullptr, nullptr, nullptr, R2, nullptr, M);
    // s8: lft0 = tanh(n1 @ Wl0 + bl0) + n1 -> lft0_bf
    mfma_ep<true,true,false,true,false,false,false,true,true><<<gm64,blk,0,stream>>>(
        n1_bf, Wl0t, bl, n1_bf, nullptr, nullptr, nullptr, lft0_bf, M);
    // s9: lft = tanh(lft0 @ Wl1 + bl1) -> R1 final
    mfma_ep<true,true,false,false,false,false,true,false,true><<<gm64,blk,0,stream>>>(
        lft0_bf, Wl1t, bl + 128, nullptr, nullptr, nullptr, R1, nullptr, M);
    // s7: emb = l2norm(accf @ Wemb + bemb) -> R0 final (last: frees R0 scratch)
    mfma_ep<false,false,true,false,false,false,true,false,true><<<gm64,blk,0,stream>>>(
        accf, Wembt, bemb, nullptr, nullptr, nullptr, R0, nullptr, M);
}

// Round 13
// 832.567 us; speedup vs baseline: 1.1310x; 1.0873x over previous
//
#include <hip/hip_runtime.h>
#include <math.h>

typedef short bf16x8 __attribute__((ext_vector_type(8)));
typedef float f32x4  __attribute__((ext_vector_type(4)));

__device__ __forceinline__ unsigned short f2bf(float x) {
    unsigned u = __float_as_uint(x);
    unsigned r = u + 0x7FFFu + ((u >> 16) & 1u);   // RNE
    return (unsigned short)(r >> 16);
}
__device__ __forceinline__ float bf2f(unsigned short b) {
    return __uint_as_float(((unsigned)b) << 16);
}
__device__ __forceinline__ bf16x8 ld_f32x8_as_bf(const float* p) {
    float4 a = *(const float4*)p;
    float4 b = *(const float4*)(p + 4);
    bf16x8 v;
    v[0] = (short)f2bf(a.x); v[1] = (short)f2bf(a.y);
    v[2] = (short)f2bf(a.z); v[3] = (short)f2bf(a.w);
    v[4] = (short)f2bf(b.x); v[5] = (short)f2bf(b.y);
    v[6] = (short)f2bf(b.z); v[7] = (short)f2bf(b.w);
    return v;
}

// ============ weight convert+transpose, epilogue-coalescing permutation ============
// PERM=1 (mfma_direct): 64-col group, col c -> row (c&3)*16+(c>>2)  => lane lr slot n = col 4lr+n
// PERM=2 (mfma_ep/tail): 128-col group, col c -> row (c&7)*16+(c>>3) => lane lr slot n = col 8lr+n
template<int PERM>
__global__ __launch_bounds__(256)
void wconv(const float* __restrict__ W, unsigned short* __restrict__ Wt, int K, int N)
{
    int id = blockIdx.x * 256 + threadIdx.x;
    if (id >= K * N) return;
    int c = id / K, k = id - c * K;
    int p;
    if (PERM == 1) {
        int hi = c & ~63, c64 = c & 63;
        p = hi + ((c64 & 3) << 4) + (c64 >> 2);
    } else {
        int hi = c & ~127, c7 = c & 127;
        p = hi + ((c7 & 7) << 4) + (c7 >> 3);
    }
    Wt[(size_t)p * K + k] = f2bf(W[(size_t)k * N + c]);
}

// all seven 128x128 tail weights (PERM=2) in one launch:
// dst order: Wg0,Wg1,Wemb,Wl0,Wl1,Wr0,Wr1
__global__ __launch_bounds__(256)
void wconv7(const float* __restrict__ Wg, const float* __restrict__ Wemb,
            const float* __restrict__ Wl, const float* __restrict__ Wr,
            unsigned short* __restrict__ dst)
{
    int id = blockIdx.x * 256 + threadIdx.x;    // < 7*16384
    if (id >= 7 * 16384) return;
    int m = id >> 14, r = id & 16383;
    int c = r >> 7, k = r & 127;
    const float* src = (m < 2) ? (Wg + m * 16384)
                     : (m == 2) ? Wemb
                     : (m < 5) ? (Wl + (m - 3) * 16384)
                               : (Wr + (m - 5) * 16384);
    int p = ((c & 7) << 4) + (c >> 3);
    dst[(size_t)m * 16384 + p * 128 + k] = f2bf(src[(size_t)k * 128 + c]);
}

// ============ bulk f32 -> bf16 ============
__global__ __launch_bounds__(256)
void f32_to_bf16(const float* __restrict__ in, unsigned short* __restrict__ outb, long n8)
{
    long id = (long)blockIdx.x * 256 + threadIdx.x;
    if (id >= n8) return;
    const float4* p = (const float4*)(in + id * 8);
    float4 a = p[0], b = p[1];
    *(ushort4*)(outb + id * 8)     = make_ushort4(f2bf(a.x), f2bf(a.y), f2bf(a.z), f2bf(a.w));
    *(ushort4*)(outb + id * 8 + 4) = make_ushort4(f2bf(b.x), f2bf(b.y), f2bf(b.z), f2bf(b.w));
}

// ============ LDS-free MFMA GEMM (R12-proven) ============
__global__ __launch_bounds__(256)
void mfma_direct(const unsigned short* __restrict__ Ab, const unsigned short* __restrict__ Wt,
                 const float* __restrict__ bias, unsigned short* __restrict__ out_bf,
                 int M, int K, int Ncols)
{
    const int tid  = threadIdx.x;
    const int row0 = blockIdx.x * 128;
    const int col0 = blockIdx.y * 128;
    const int wv   = tid >> 6, lane = tid & 63;
    const int wr   = (wv >> 1) * 64, wc = (wv & 1) * 64;
    const int lr   = lane & 15;
    const int lk8  = (lane >> 4) * 8;

    const unsigned short* arow[4];
    const unsigned short* brow[4];
#pragma unroll
    for (int m = 0; m < 4; m++) {
        int r = row0 + wr + m * 16 + lr;
        r = r < M ? r : (M - 1);
        arow[m] = Ab + (size_t)r * K + lk8;
    }
#pragma unroll
    for (int n = 0; n < 4; n++)
        brow[n] = Wt + (size_t)(col0 + wc + n * 16 + lr) * K + lk8;

    f32x4 acc[4][4];
#pragma unroll
    for (int m = 0; m < 4; m++)
#pragma unroll
        for (int n = 0; n < 4; n++)
#pragma unroll
            for (int j = 0; j < 4; j++) acc[m][n][j] = 0.f;

#pragma unroll 2
    for (int kk = 0; kk < K; kk += 32) {
        bf16x8 af[4], bfr[4];
#pragma unroll
        for (int m = 0; m < 4; m++) af[m]  = *(const bf16x8*)(arow[m] + kk);
#pragma unroll
        for (int n = 0; n < 4; n++) bfr[n] = *(const bf16x8*)(brow[n] + kk);
#pragma unroll
        for (int m = 0; m < 4; m++)
#pragma unroll
            for (int n = 0; n < 4; n++)
                acc[m][n] = __builtin_amdgcn_mfma_f32_16x16x32_bf16(af[m], bfr[n], acc[m][n], 0, 0, 0);
    }

    const int cbase = col0 + wc + lr * 4;
    float4 b4 = *(const float4*)(bias + cbase);
    float bv[4] = {b4.x, b4.y, b4.z, b4.w};
    const int rbase = (lane >> 4) * 4;
#pragma unroll
    for (int m = 0; m < 4; m++) {
#pragma unroll
        for (int j = 0; j < 4; j++) {
            int row = row0 + wr + m * 16 + rbase + j;
            if (row < M) {
                ushort4 o;
                o.x = f2bf(tanhf(acc[m][0][j] + bv[0]));
                o.y = f2bf(tanhf(acc[m][1][j] + bv[1]));
                o.z = f2bf(tanhf(acc[m][2][j] + bv[2]));
                o.w = f2bf(tanhf(acc[m][3][j] + bv[3]));
                *(ushort4*)(out_bf + (size_t)row * Ncols + cbase) = o;
            }
        }
    }
}

// ============ MFMA K=128 single-tile, fused epilogue (R12-proven; used for s4) ============
template<bool ABF16, bool TANH, bool L2, bool RESID, bool AUX, bool AUXBF,
         bool F32OUT, bool BF16OUT, bool BIAS>
__global__ __launch_bounds__(256)
void mfma_ep(const void* __restrict__ A_, const unsigned short* __restrict__ Wt,
             const float* __restrict__ bias, const unsigned short* __restrict__ resid_bf,
             const void* __restrict__ aux_in, float* __restrict__ aux_out,
             float* __restrict__ out, unsigned short* __restrict__ out_bf, int M)
{
    const int tid  = threadIdx.x;
    const int row0 = blockIdx.x * 64;
    const int wv   = tid >> 6, lane = tid & 63;
    const int lr   = lane & 15;
    const int lk8  = (lane >> 4) * 8;
    const int wr   = wv * 16;

    const unsigned short* Abr;
    const float*          Afr;
    {
        int r = row0 + wr + lr;
        r = r < M ? r : (M - 1);
        Abr = (const unsigned short*)A_ + ((size_t)r << 7) + lk8;
        Afr = (const float*)A_          + ((size_t)r << 7) + lk8;
    }

    f32x4 acc[8];
#pragma unroll
    for (int n = 0; n < 8; n++)
#pragma unroll
        for (int j = 0; j < 4; j++) acc[n][j] = 0.f;

#pragma unroll 2
    for (int ks = 0; ks < 4; ks++) {
        bf16x8 af, bn[8];
        if (ABF16) af = *(const bf16x8*)(Abr + ks * 32);
        else       af = ld_f32x8_as_bf(Afr + ks * 32);
#pragma unroll
        for (int n = 0; n < 8; n++)
            bn[n] = *(const bf16x8*)(Wt + (((size_t)(n * 16 + lr)) << 7) + ks * 32 + lk8);
#pragma unroll
        for (int n = 0; n < 8; n++)
            acc[n] = __builtin_amdgcn_mfma_f32_16x16x32_bf16(af, bn[n], acc[n], 0, 0, 0);
    }

    const int cbase = lr * 8;
    float bv[8];
    if (BIAS) {
        float4 b0 = *(const float4*)(bias + cbase);
        float4 b1 = *(const float4*)(bias + cbase + 4);
        bv[0]=b0.x; bv[1]=b0.y; bv[2]=b0.z; bv[3]=b0.w;
        bv[4]=b1.x; bv[5]=b1.y; bv[6]=b1.z; bv[7]=b1.w;
    } else {
#pragma unroll
        for (int n = 0; n < 8; n++) bv[n] = 0.f;
    }
    const int rbase = (lane >> 4) * 4;

#pragma unroll
    for (int j = 0; j < 4; j++) {
        int row = row0 + wr + rbase + j;
        bool ok = row < M;
        size_t base = ((size_t)row << 7) + cbase;
        float v[8];
#pragma unroll
        for (int n = 0; n < 8; n++) {
            v[n] = acc[n][j] + bv[n];
            if (TANH) v[n] = tanhf(v[n]);
        }
        if (RESID) {
            if (ok) {
                bf16x8 rv = *(const bf16x8*)(resid_bf + base);
#pragma unroll
                for (int n = 0; n < 8; n++) v[n] += bf2f((unsigned short)rv[n]);
            }
        }
        if (L2) {
            float s = 0.f;
#pragma unroll
            for (int n = 0; n < 8; n++) s += v[n] * v[n];
#pragma unroll
            for (int msk = 8; msk >= 1; msk >>= 1) s += __shfl_xor(s, msk);
            float sc = 1.f / fmaxf(sqrtf(s), 1e-12f);
#pragma unroll
            for (int n = 0; n < 8; n++) v[n] *= sc;
        }
        if (ok) {
            if (F32OUT) {
                *(float4*)(out + base)     = make_float4(v[0], v[1], v[2], v[3]);
                *(float4*)(out + base + 4) = make_float4(v[4], v[5], v[6], v[7]);
            }
            if (BF16OUT) {
                bf16x8 o;
#pragma unroll
                for (int n = 0; n < 8; n++) o[n] = (short)f2bf(v[n]);
                *(bf16x8*)(out_bf + base) = o;
            }
            if (AUX) {
                float ai[8];
                if (AUXBF) {
                    bf16x8 av = *(const bf16x8*)((const unsigned short*)aux_in + base);
#pragma unroll
                    for (int n = 0; n < 8; n++) ai[n] = bf2f((unsigned short)av[n]);
                } else {
                    float4 a0 = *(const float4*)((const float*)aux_in + base);
                    float4 a1 = *(const float4*)((const float*)aux_in + base + 4);
                    ai[0]=a0.x; ai[1]=a0.y; ai[2]=a0.z; ai[3]=a0.w;
                    ai[4]=a1.x; ai[5]=a1.y; ai[6]=a1.z; ai[7]=a1.w;
                }
                *(float4*)(aux_out + base)     = make_float4(ai[0]+v[0], ai[1]+v[1], ai[2]+v[2], ai[3]+v[3]);
                *(float4*)(aux_out + base + 4) = make_float4(ai[4]+v[4], ai[5]+v[5], ai[6]+v[6], ai[7]+v[7]);
            }
        }
    }
}

// ============ fused tail: n1 -> acc -> emb / lft0 -> lft / rgt0 -> rgt ============
// One kernel replaces s6..s11. Per-wave 16 rows; LDS slice re-shapes epilogue values
// into A-fragments (in-order per-wave DS, no barriers). Wt7 = 7x[128][128] PERM=2.
__global__ __launch_bounds__(256)
void tail_fused(const unsigned short* __restrict__ h_bf, const float* __restrict__ accf,
                const unsigned short* __restrict__ Wt7,
                const float* __restrict__ bemb, const float* __restrict__ bl,
                const float* __restrict__ br,
                float* __restrict__ embO, float* __restrict__ lftO,
                float* __restrict__ rgtO, int M)
{
    __shared__ __align__(16) unsigned short ldsA[4][16][136];  // n1
    __shared__ __align__(16) unsigned short ldsB[4][16][136];  // acc / lft0 / rgt0

    const int tid = threadIdx.x;
    const int wv = tid >> 6, lane = tid & 63;
    const int lr = lane & 15;
    const int lk8 = (lane >> 4) * 8;
    const int rbase = (lane >> 4) * 4;
    const int row0 = blockIdx.x * 64 + wv * 16;
    const int cbase = lr * 8;

    const unsigned short* Wg1t  = Wt7 + 1 * 16384;
    const unsigned short* Wembt = Wt7 + 2 * 16384;
    const unsigned short* Wl0t  = Wt7 + 3 * 16384;
    const unsigned short* Wl1t  = Wt7 + 4 * 16384;
    const unsigned short* Wr0t  = Wt7 + 5 * 16384;
    const unsigned short* Wr1t  = Wt7 + 6 * 16384;

    f32x4 acc[8];

#define ZACC() { _Pragma("unroll") for (int n = 0; n < 8; n++) \
                 _Pragma("unroll") for (int q = 0; q < 4; q++) acc[n][q] = 0.f; }
#define MM128(AFRAG, WPTR)                                                            \
    _Pragma("unroll")                                                                 \
    for (int ks = 0; ks < 4; ks++) {                                                  \
        bf16x8 af = (AFRAG);                                                          \
        bf16x8 bn[8];                                                                 \
        _Pragma("unroll")                                                             \
        for (int n = 0; n < 8; n++)                                                   \
            bn[n] = *(const bf16x8*)((WPTR) + (((size_t)(n * 16 + lr)) << 7) + ks * 32 + lk8); \
        _Pragma("unroll")                                                             \
        for (int n = 0; n < 8; n++)                                                   \
            acc[n] = __builtin_amdgcn_mfma_f32_16x16x32_bf16(af, bn[n], acc[n], 0, 0, 0); \
    }
#define LDBIAS(BV, P) { float4 b0_ = *(const float4*)((P) + cbase);                   \
                        float4 b1_ = *(const float4*)((P) + cbase + 4);               \
                        BV[0]=b0_.x; BV[1]=b0_.y; BV[2]=b0_.z; BV[3]=b0_.w;           \
                        BV[4]=b1_.x; BV[5]=b1_.y; BV[6]=b1_.z; BV[7]=b1_.w; }
#define L2NORM(V) { float s_ = 0.f;                                                   \
                    _Pragma("unroll") for (int n = 0; n < 8; n++) s_ += V[n]*V[n];    \
                    _Pragma("unroll") for (int mk = 8; mk >= 1; mk >>= 1) s_ += __shfl_xor(s_, mk); \
                    float sc_ = 1.f / fmaxf(sqrtf(s_), 1e-12f);                       \
                    _Pragma("unroll") for (int n = 0; n < 8; n++) V[n] *= sc_; }

    // ---- stage 1: n1 = l2norm(tanh(h @ Wg1)); acc = accf + n1 ----
    const unsigned short* hrow;
    {
        int r = row0 + lr;
        r = r < M ? r : (M - 1);
        hrow = h_bf + ((size_t)r << 7) + lk8;
    }
    ZACC();
    MM128(*(const bf16x8*)(hrow + ks * 32), Wg1t);
#pragma unroll
    for (int j = 0; j < 4; j++) {
        int row = row0 + rbase + j;
        int rc = row < M ? row : (M - 1);
        float v[8];
#pragma unroll
        for (int n = 0; n < 8; n++) v[n] = tanhf(acc[n][j]);
        L2NORM(v);
        bf16x8 o;
#pragma unroll
        for (int n = 0; n < 8; n++) o[n] = (short)f2bf(v[n]);
        *(bf16x8*)&ldsA[wv][rbase + j][cbase] = o;
        float4 a0 = *(const float4*)(accf + ((size_t)rc << 7) + cbase);
        float4 a1 = *(const float4*)(accf + ((size_t)rc << 7) + cbase + 4);
        float av[8] = {a0.x+v[0], a0.y+v[1], a0.z+v[2], a0.w+v[3],
                       a1.x+v[4], a1.y+v[5], a1.z+v[6], a1.w+v[7]};
        bf16x8 ob;
#pragma unroll
        for (int n = 0; n < 8; n++) ob[n] = (short)f2bf(av[n]);
        *(bf16x8*)&ldsB[wv][rbase + j][cbase] = ob;
    }

    // ---- stage 2: emb = l2norm(acc @ Wemb + bemb) ----
    ZACC();
    MM128(*(const bf16x8*)&ldsB[wv][lr][ks * 32 + lk8], Wembt);
    {
        float bv[8]; LDBIAS(bv, bemb);
#pragma unroll
        for (int j = 0; j < 4; j++) {
            int row = row0 + rbase + j;
            float v[8];
#pragma unroll
            for (int n = 0; n < 8; n++) v[n] = acc[n][j] + bv[n];
            L2NORM(v);
            if (row < M) {
                size_t base = ((size_t)row << 7) + cbase;
                *(float4*)(embO + base)     = make_float4(v[0], v[1], v[2], v[3]);
                *(float4*)(embO + base + 4) = make_float4(v[4], v[5], v[6], v[7]);
            }
        }
    }

    // ---- stage 3: lft0 = tanh(n1 @ Wl0 + bl0) + n1 ----
    ZACC();
    MM128(*(const bf16x8*)&ldsA[wv][lr][ks * 32 + lk8], Wl0t);
    {
        float bv[8]; LDBIAS(bv, bl);
#pragma unroll
        for (int j = 0; j < 4; j++) {
            bf16x8 rv = *(const bf16x8*)&ldsA[wv][rbase + j][cbase];
            bf16x8 ob;
#pragma unroll
            for (int n = 0; n < 8; n++)
                ob[n] = (short)f2bf(tanhf(acc[n][j] + bv[n]) + bf2f((unsigned short)rv[n]));
            *(bf16x8*)&ldsB[wv][rbase + j][cbase] = ob;
        }
    }

    // ---- stage 4: lft = tanh(lft0 @ Wl1 + bl1) ----
    ZACC();
    MM128(*(const bf16x8*)&ldsB[wv][lr][ks * 32 + lk8], Wl1t);
    {
        float bv[8]; LDBIAS(bv, bl + 128);
#pragma unroll
        for (int j = 0; j < 4; j++) {
            int row = row0 + rbase + j;
            if (row < M) {
                size_t base = ((size_t)row << 7) + cbase;
                *(float4*)(lftO + base)     = make_float4(tanhf(acc[0][j]+bv[0]), tanhf(acc[1][j]+bv[1]),
                                                          tanhf(acc[2][j]+bv[2]), tanhf(acc[3][j]+bv[3]));
                *(float4*)(lftO + base + 4) = make_float4(tanhf(acc[4][j]+bv[4]), tanhf(acc[5][j]+bv[5]),
                                                          tanhf(acc[6][j]+bv[6]), tanhf(acc[7][j]+bv[7]));
            }
        }
    }

    // ---- stage 5: rgt0 = tanh(n1 @ Wr0 + br0) + n1 ----
    ZACC();
    MM128(*(const bf16x8*)&ldsA[wv][lr][ks * 32 + lk8], Wr0t);
    {
        float bv[8]; LDBIAS(bv, br);
#pragma unroll
        for (int j = 0; j < 4; j++) {
            bf16x8 rv = *(const bf16x8*)&ldsA[wv][rbase + j][cbase];
            bf16x8 ob;
#pragma unroll
            for (int n = 0; n < 8; n++)
                ob[n] = (short)f2bf(tanhf(acc[n][j] + bv[n]) + bf2f((unsigned short)rv[n]));
            *(bf16x8*)&ldsB[wv][rbase + j][cbase] = ob;
        }
    }

    // ---- stage 6: rgt = tanh(rgt0 @ Wr1 + br1) ----
    ZACC();
    MM128(*(const bf16x8*)&ldsB[wv][lr][ks * 32 + lk8], Wr1t);
    {
        float bv[8]; LDBIAS(bv, br + 128);
#pragma unroll
        for (int j = 0; j < 4; j++) {
            int row = row0 + rbase + j;
            if (row < M) {
                size_t base = ((size_t)row << 7) + cbase;
                *(float4*)(rgtO + base)     = make_float4(tanhf(acc[0][j]+bv[0]), tanhf(acc[1][j]+bv[1]),
                                                          tanhf(acc[2][j]+bv[2]), tanhf(acc[3][j]+bv[3]));
                *(float4*)(rgtO + base + 4) = make_float4(tanhf(acc[4][j]+bv[4]), tanhf(acc[5][j]+bv[5]),
                                                          tanhf(acc[6][j]+bv[6]), tanhf(acc[7][j]+bv[7]));
            }
        }
    }
#undef ZACC
#undef MM128
#undef LDBIAS
#undef L2NORM
}

// ============ bucketed CSR build ============
#define RCHUNK 16384

__global__ __launch_bounds__(256)
void bhist_k(const int* __restrict__ rows, int* __restrict__ bcnt, int E, int NB)
{
    __shared__ int lc[1024];
    for (int b = threadIdx.x; b < NB; b += 256) lc[b] = 0;
    __syncthreads();
    int start = blockIdx.x * RCHUNK;
    int end = min(start + RCHUNK, E);
    for (int i = start + threadIdx.x; i < end; i += 256)
        atomicAdd(&lc[rows[i] >> 7], 1);
    __syncthreads();
    for (int b = threadIdx.x; b < NB; b += 256)
        if (lc[b]) atomicAdd(&bcnt[b], lc[b]);
}

// single-block exclusive scan of bcnt -> bbase (and bcur copy); NB <= 1024
__global__ __launch_bounds__(256)
void bucket_scan(const int* __restrict__ bcnt, int* __restrict__ bbase,
                 int* __restrict__ bcur, int NB)
{
    __shared__ int sdata[256];
    const int tid = threadIdx.x;
    int loc[4]; int s = 0;
#pragma unroll
    for (int j = 0; j < 4; j++) {
        int i = tid * 4 + j;
        int v = (i < NB) ? bcnt[i] : 0;
        loc[j] = s; s += v;
    }
    sdata[tid] = s;
    __syncthreads();
    int x = s;
    for (int off = 1; off < 256; off <<= 1) {
        int t = 0;
        if (tid >= off) t = sdata[tid - off];
        __syncthreads();
        x += t;
        sdata[tid] = x;
        __syncthreads();
    }
    int excl = x - s;
#pragma unroll
    for (int j = 0; j < 4; j++) {
        int i = tid * 4 + j;
        if (i < NB) { bbase[i] = excl + loc[j]; bcur[i] = excl + loc[j]; }
    }
    if (tid == 255) bbase[NB] = x;
}

__global__ __launch_bounds__(256)
void bucket_scatter(const int* __restrict__ rows, const int* __restrict__ cols,
                    const float* __restrict__ vals, int* __restrict__ bcur,
                    int2* __restrict__ tmp, int E, int NB)
{
    __shared__ int lcnt[1024];
    __shared__ int lbase[1024];
    for (int b = threadIdx.x; b < NB; b += 256) lcnt[b] = 0;
    __syncthreads();
    int start = blockIdx.x * RCHUNK;
    int end = min(start + RCHUNK, E);
    for (int i = start + threadIdx.x; i < end; i += 256)
        atomicAdd(&lcnt[rows[i] >> 7], 1);
    __syncthreads();
    for (int b = threadIdx.x; b < NB; b += 256) {
        int c = lcnt[b];
        lbase[b] = c ? atomicAdd(&bcur[b], c) : 0;
        lcnt[b] = 0;
    }
    __syncthreads();
    for (int i = start + threadIdx.x; i < end; i += 256) {
        int r = rows[i];
        int b = r >> 7;
        int off = atomicAdd(&lcnt[b], 1);
        tmp[lbase[b] + off] = make_int2(cols[i] | ((r & 127) << 17), __float_as_int(vals[i]));
    }
}

__global__ __launch_bounds__(256)
void csr_place(const int2* __restrict__ tmp, const int* __restrict__ bbase,
               int* __restrict__ rowptr, int2* __restrict__ packed, int M, int NB)
{
    __shared__ int lcnt[128];
    __shared__ int lofs[128];
    const int tid = threadIdx.x;
    const int b = blockIdx.x;
    const int s = bbase[b], e = bbase[b + 1];
    const int rb = b << 7;
    if (tid < 128) lcnt[tid] = 0;
    __syncthreads();
    for (int i = s + tid; i < e; i += 256)
        atomicAdd(&lcnt[(((unsigned)tmp[i].x) >> 17) & 127], 1);
    __syncthreads();
    if (tid == 0) {
        int run = s;
#pragma unroll 8
        for (int r = 0; r < 128; r++) { lofs[r] = run; run += lcnt[r]; }
    }
    __syncthreads();
    if (tid < 128 && rb + tid < M) rowptr[rb + tid] = lofs[tid];
    if (b == NB - 1 && tid == 0) rowptr[M] = e;
    if (tid < 128) lcnt[tid] = 0;
    __syncthreads();
    for (int i = s + tid; i < e; i += 256) {
        int2 t = tmp[i];
        int rl = (((unsigned)t.x) >> 17) & 127;
        int pos = lofs[rl] + atomicAdd(&lcnt[rl], 1);
        packed[pos] = make_int2(t.x & 0x1FFFF, t.y);
    }
}

// ============ CSR SpMM: 16 lanes/edge x 4 edge-groups, 16B gathers ============
__global__ __launch_bounds__(256)
void spmm_csr(const int* __restrict__ rowptr, const int2* __restrict__ packed,
              const unsigned short* __restrict__ embb, unsigned short* __restrict__ hb, int N)
{
    const int wv = threadIdx.x >> 6, lane = threadIdx.x & 63;
    const int g = lane >> 4, q = lane & 15;
    const int r = blockIdx.x * 4 + wv;
    if (r >= N) return;
    const int s = rowptr[r], e = rowptr[r + 1];
    const unsigned short* __restrict__ eb = embb + q * 8;

    float a0=0.f,a1=0.f,a2=0.f,a3=0.f,a4=0.f,a5=0.f,a6=0.f,a7=0.f;
    int i = s + g;
    for (; i + 12 < e; i += 16) {
#pragma unroll
        for (int u = 0; u < 4; u++) {
            int2 p = packed[i + 4 * u];
            uint4 m = *(const uint4*)(eb + ((size_t)p.x << 7));
            float v = __int_as_float(p.y);
            a0 += v * __uint_as_float(m.x << 16);
            a1 += v * __uint_as_float(m.x & 0xffff0000u);
            a2 += v * __uint_as_float(m.y << 16);
            a3 += v * __uint_as_float(m.y & 0xffff0000u);
            a4 += v * __uint_as_float(m.z << 16);
            a5 += v * __uint_as_float(m.z & 0xffff0000u);
            a6 += v * __uint_as_float(m.w << 16);
            a7 += v * __uint_as_float(m.w & 0xffff0000u);
        }
    }
    for (; i < e; i += 4) {
        int2 p = packed[i];
        uint4 m = *(const uint4*)(eb + ((size_t)p.x << 7));
        float v = __int_as_float(p.y);
        a0 += v * __uint_as_float(m.x << 16);
        a1 += v * __uint_as_float(m.x & 0xffff0000u);
        a2 += v * __uint_as_float(m.y << 16);
        a3 += v * __uint_as_float(m.y & 0xffff0000u);
        a4 += v * __uint_as_float(m.z << 16);
        a5 += v * __uint_as_float(m.z & 0xffff0000u);
        a6 += v * __uint_as_float(m.w << 16);
        a7 += v * __uint_as_float(m.w & 0xffff0000u);
    }
#pragma unroll
    for (int msk = 16; msk <= 32; msk <<= 1) {
        a0 += __shfl_xor(a0, msk); a1 += __shfl_xor(a1, msk);
        a2 += __shfl_xor(a2, msk); a3 += __shfl_xor(a3, msk);
        a4 += __shfl_xor(a4, msk); a5 += __shfl_xor(a5, msk);
        a6 += __shfl_xor(a6, msk); a7 += __shfl_xor(a7, msk);
    }
    if (g == 0) {
        unsigned o0 = (unsigned)f2bf(a0) | ((unsigned)f2bf(a1) << 16);
        unsigned o1 = (unsigned)f2bf(a2) | ((unsigned)f2bf(a3) << 16);
        unsigned o2 = (unsigned)f2bf(a4) | ((unsigned)f2bf(a5) << 16);
        unsigned o3 = (unsigned)f2bf(a6) | ((unsigned)f2bf(a7) << 16);
        *(uint4*)(hb + ((size_t)r << 7) + q * 8) = make_uint4(o0, o1, o2, o3);
    }
}

// ============ launch ============
extern "C" void kernel_launch(void* const* d_in, const int* in_sizes, int n_in,
                              void* d_out, int out_size, void* d_ws, size_t ws_size,
                              hipStream_t stream)
{
    const float* feat  = (const float*)d_in[0];
    const int*   srows = (const int*)  d_in[1];
    const int*   scols = (const int*)  d_in[2];
    const float* svals = (const float*)d_in[3];
    const float* Wf0   = (const float*)d_in[4];
    const float* bf0   = (const float*)d_in[5];
    const float* Wf1   = (const float*)d_in[6];
    const float* bf1   = (const float*)d_in[7];
    const float* Wg    = (const float*)d_in[8];
    const float* Wemb  = (const float*)d_in[9];
    const float* bemb  = (const float*)d_in[10];
    const float* Wl    = (const float*)d_in[11];
    const float* bl    = (const float*)d_in[12];
    const float* Wr    = (const float*)d_in[13];
    const float* br    = (const float*)d_in[14];

    const int M = in_sizes[0] / 512;   // 100000 nodes
    const int E = in_sizes[1];         // 3200000 edges
    const int NB = (M + 127) >> 7;     // 782 buckets

    float* out = (float*)d_out;
    float* R0 = out;                        // emb final
    float* R1 = out + (size_t)M * 128;      // lft final
    float* R2 = out + (size_t)M * 256;      // rgt final

    // ---- ws layout (~103.5 MB; harness provides >=128 MB, proven R1) ----
    float* ws = (float*)d_ws;
    float* accf = ws;                                      // [M,128] f32; tmp aliases (dead before s4)
    int2*  tmp  = (int2*)ws;
    int*   ip = (int*)(ws + (size_t)M * 128);
    int*   rowptr  = ip;                                   // M+1
    int2*  packed  = (int2*)(ip + (((size_t)M + 4) & ~(size_t)3));  // E
    int*   bcnt    = (int*)(packed + E);                   // 1024
    int*   bbase   = bcnt + 1024;                          // 1032
    int*   bcur    = bbase + 1032;                         // 1024
    unsigned short* h_ws = (unsigned short*)(bcur + 1024); // [M,128] bf16 spmm accumulator
    unsigned short* Wt0  = h_ws + (size_t)M * 128;         // [256][512]
    unsigned short* Wt1  = Wt0 + 256 * 512;                // [128][256]
    unsigned short* Wt7  = Wt1 + 128 * 256;                // 7 x [128][128]: Wg0,Wg1,Wemb,Wl0,Wl1,Wr0,Wr1

    // ---- d_out scratch timeline ----
    unsigned short* R0a = (unsigned short*)R0;
    unsigned short* R1a = (unsigned short*)R1;
    unsigned short* feat_bf = (unsigned short*)R0;  // [M,512] = R0+R1, dead after s1
    unsigned short* x1_bf   = (unsigned short*)R2;  // [M,256], dead after s2
    unsigned short* x_bf    = R0a;                  // s2 out; spmm3 src; s4 aux
    unsigned short* n0_bf   = R1a;                  // s4 -> spmm5, dead after
    // tail writes R0/R1/R2 f32 directly; all bf16 scratch in d_out dead by then

    dim3 blk(256);
    const int gm128 = (M + 127) / 128;
    const int gm64  = (M + 63) / 64;
    const int nch   = (E + RCHUNK - 1) / RCHUNK;

    // weight converts (3 launches)
    wconv<1><<<(512*256 + 255)/256, blk, 0, stream>>>(Wf0, Wt0, 512, 256);
    wconv<1><<<(256*128 + 255)/256, blk, 0, stream>>>(Wf1, Wt1, 256, 128);
    wconv7<<<(7*16384 + 255)/256, blk, 0, stream>>>(Wg, Wemb, Wl, Wr, Wt7);

    // feat -> bf16
    f32_to_bf16<<<(int)(((long)M * 64 + 255) / 256), blk, 0, stream>>>(feat, feat_bf, (long)M * 64);

    // ---- CSR build ----
    hipMemsetAsync(bcnt, 0, (size_t)NB * 4, stream);
    bhist_k<<<nch, blk, 0, stream>>>(srows, bcnt, E, NB);
    bucket_scan<<<1, blk, 0, stream>>>(bcnt, bbase, bcur, NB);
    bucket_scatter<<<nch, blk, 0, stream>>>(srows, scols, svals, bcur, tmp, E, NB);
    csr_place<<<NB, blk, 0, stream>>>(tmp, bbase, rowptr, packed, M, NB);

    // ---- network ----
    // s1: x1_bf = tanh(feat @ Wf0 + bf0)
    mfma_direct<<<dim3(gm128,2),blk,0,stream>>>(feat_bf, Wt0, bf0, x1_bf, M, 512, 256);
    // s2: x_bf = tanh(x1 @ Wf1 + bf1)
    mfma_direct<<<dim3(gm128,1),blk,0,stream>>>(x1_bf, Wt1, bf1, x_bf, M, 256, 128);
    // spmm3: h = S @ x
    spmm_csr<<<(M + 3) / 4, blk, 0, stream>>>(rowptr, packed, x_bf, h_ws, M);
    // s4: n0 = l2norm(tanh(h @ Wg0)) -> n0_bf; accf = x + n0
    mfma_ep<true,true,true,false,true,true,false,true,false><<<gm64,blk,0,stream>>>(
        h_ws, Wt7 /*Wg0t*/, nullptr, nullptr, x_bf, accf, nullptr, n0_bf, M);
    // spmm5: h = S @ n0
    spmm_csr<<<(M + 3) / 4, blk, 0, stream>>>(rowptr, packed, n0_bf, h_ws, M);
    // tail: n1 -> acc -> emb(R0) / lft(R1) / rgt(R2)
    tail_fused<<<gm64, blk, 0, stream>>>(h_ws, accf, Wt7, bemb, bl, br, R0, R1, R2, M);
}

// Round 14
// 727.554 us; speedup vs baseline: 1.2942x; 1.1443x over previous
//
#include <hip/hip_runtime.h>
#include <math.h>

typedef short bf16x8 __attribute__((ext_vector_type(8)));
typedef float f32x4  __attribute__((ext_vector_type(4)));

__device__ __forceinline__ unsigned short f2bf(float x) {
    unsigned u = __float_as_uint(x);
    unsigned r = u + 0x7FFFu + ((u >> 16) & 1u);   // RNE
    return (unsigned short)(r >> 16);
}
__device__ __forceinline__ float bf2f(unsigned short b) {
    return __uint_as_float(((unsigned)b) << 16);
}

// ============ weight converts -> FRAGMENT-MAJOR layouts ============
// Layout D (mfma_direct): chunk (kblk=k/32, cblk=c/64, n=c&3) holds 64 lanes x 8 elems;
//   lane = (c>>2)&15 | ((k>>3)&3)<<4 ; elem = k&7.
//   Kernel: bfr[n] = Wt[ ((kblk*ncb + cblk)*4 + n)*512 + lane*8 ]  (coalesced 1024B)
//   Epilogue mapping: lane lr slot n = logical col (64-blk base) + 4*lr + n
__global__ __launch_bounds__(256)
void wconvD(const float* __restrict__ W, unsigned short* __restrict__ Wt, int K, int N)
{
    int id = blockIdx.x * 256 + threadIdx.x;
    if (id >= K * N) return;
    int c = id / K, k = id - c * K;
    int kblk = k >> 5, ksub = (k >> 3) & 3, kel = k & 7;
    int cblk = c >> 6, n = c & 3, lr = (c >> 2) & 15;
    int lane = lr + (ksub << 4);
    size_t dst = ((((size_t)kblk * (N >> 6) + cblk) * 4 + n) << 9) + (lane << 3) + kel;
    Wt[dst] = f2bf(W[(size_t)k * N + c]);
}

// Layout E (128-wide ep/tail): chunk (ks=k/32, n=c&7); lane = (c>>3)&15 | ((k>>3)&3)<<4.
//   Kernel: bn[n] = Wt[ ((ks*8+n)*512 + lane*8) ]. Epilogue: lane lr slot n = col 8*lr+n.
// all seven 128x128 tail weights in one launch: Wg0,Wg1,Wemb,Wl0,Wl1,Wr0,Wr1
__global__ __launch_bounds__(256)
void wconv7(const float* __restrict__ Wg, const float* __restrict__ Wemb,
            const float* __restrict__ Wl, const float* __restrict__ Wr,
            unsigned short* __restrict__ dst)
{
    int id = blockIdx.x * 256 + threadIdx.x;    // < 7*16384
    if (id >= 7 * 16384) return;
    int m = id >> 14, r = id & 16383;
    int c = r >> 7, k = r & 127;
    const float* src = (m < 2) ? (Wg + m * 16384)
                     : (m == 2) ? Wemb
                     : (m < 5) ? (Wl + (m - 3) * 16384)
                               : (Wr + (m - 5) * 16384);
    int n = c & 7, lr = (c >> 3) & 15;
    int ks = k >> 5, ksub = (k >> 3) & 3, kel = k & 7;
    int lane = lr + (ksub << 4);
    dst[(size_t)m * 16384 + (((ks << 3) + n) << 9) + (lane << 3) + kel] = f2bf(src[(size_t)k * 128 + c]);
}

// ============ bulk f32 -> bf16 ============
__global__ __launch_bounds__(256)
void f32_to_bf16(const float* __restrict__ in, unsigned short* __restrict__ outb, long n8)
{
    long id = (long)blockIdx.x * 256 + threadIdx.x;
    if (id >= n8) return;
    const float4* p = (const float4*)(in + id * 8);
    float4 a = p[0], b = p[1];
    *(ushort4*)(outb + id * 8)     = make_ushort4(f2bf(a.x), f2bf(a.y), f2bf(a.z), f2bf(a.w));
    *(ushort4*)(outb + id * 8 + 4) = make_ushort4(f2bf(b.x), f2bf(b.y), f2bf(b.z), f2bf(b.w));
}

// ============ LDS-free MFMA GEMM, fragment-major B (coalesced), permuted epilogue ============
__global__ __launch_bounds__(256)
void mfma_direct(const unsigned short* __restrict__ Ab, const unsigned short* __restrict__ Wt,
                 const float* __restrict__ bias, unsigned short* __restrict__ out_bf,
                 int M, int K, int Ncols)
{
    const int tid  = threadIdx.x;
    const int row0 = blockIdx.x * 128;
    const int col0 = blockIdx.y * 128;
    const int wv   = tid >> 6, lane = tid & 63;
    const int wr   = (wv >> 1) * 64, wc = (wv & 1) * 64;
    const int lr   = lane & 15;
    const int lk8  = (lane >> 4) * 8;
    const int ncb  = Ncols >> 6;
    const int cp   = (col0 + wc) >> 6;      // 64-col panel index

    const unsigned short* arow[4];
#pragma unroll
    for (int m = 0; m < 4; m++) {
        int r = row0 + wr + m * 16 + lr;
        r = r < M ? r : (M - 1);
        arow[m] = Ab + (size_t)r * K + lk8;
    }
    const unsigned short* bb = Wt + (((size_t)cp * 4) << 9) + (lane << 3);
    const size_t bstep = (size_t)ncb * 2048;   // advance per 32-k

    f32x4 acc[4][4];
#pragma unroll
    for (int m = 0; m < 4; m++)
#pragma unroll
        for (int n = 0; n < 4; n++)
#pragma unroll
            for (int j = 0; j < 4; j++) acc[m][n][j] = 0.f;

#pragma unroll 2
    for (int kk = 0; kk < K; kk += 32) {
        bf16x8 af[4], bfr[4];
#pragma unroll
        for (int m = 0; m < 4; m++) af[m]  = *(const bf16x8*)(arow[m] + kk);
        const unsigned short* bk = bb + (size_t)(kk >> 5) * bstep;
#pragma unroll
        for (int n = 0; n < 4; n++) bfr[n] = *(const bf16x8*)(bk + (n << 9));
#pragma unroll
        for (int m = 0; m < 4; m++)
#pragma unroll
            for (int n = 0; n < 4; n++)
                acc[m][n] = __builtin_amdgcn_mfma_f32_16x16x32_bf16(af[m], bfr[n], acc[m][n], 0, 0, 0);
    }

    const int cbase = col0 + wc + lr * 4;
    float4 b4 = *(const float4*)(bias + cbase);
    float bv[4] = {b4.x, b4.y, b4.z, b4.w};
    const int rbase = (lane >> 4) * 4;
#pragma unroll
    for (int m = 0; m < 4; m++) {
#pragma unroll
        for (int j = 0; j < 4; j++) {
            int row = row0 + wr + m * 16 + rbase + j;
            if (row < M) {
                ushort4 o;
                o.x = f2bf(tanhf(acc[m][0][j] + bv[0]));
                o.y = f2bf(tanhf(acc[m][1][j] + bv[1]));
                o.z = f2bf(tanhf(acc[m][2][j] + bv[2]));
                o.w = f2bf(tanhf(acc[m][3][j] + bv[3]));
                *(ushort4*)(out_bf + (size_t)row * Ncols + cbase) = o;
            }
        }
    }
}

// ============ MFMA K=128 single-tile, fragment-major B, fused epilogue (s4) ============
template<bool ABF16, bool TANH, bool L2, bool RESID, bool AUX, bool AUXBF,
         bool F32OUT, bool BF16OUT, bool BIAS>
__global__ __launch_bounds__(256)
void mfma_ep(const void* __restrict__ A_, const unsigned short* __restrict__ Wt,
             const float* __restrict__ bias, const unsigned short* __restrict__ resid_bf,
             const void* __restrict__ aux_in, float* __restrict__ aux_out,
             float* __restrict__ out, unsigned short* __restrict__ out_bf, int M)
{
    const int tid  = threadIdx.x;
    const int row0 = blockIdx.x * 64;
    const int wv   = tid >> 6, lane = tid & 63;
    const int lr   = lane & 15;
    const int lk8  = (lane >> 4) * 8;
    const int wr   = wv * 16;

    const unsigned short* Abr;
    const float*          Afr;
    {
        int r = row0 + wr + lr;
        r = r < M ? r : (M - 1);
        Abr = (const unsigned short*)A_ + ((size_t)r << 7) + lk8;
        Afr = (const float*)A_          + ((size_t)r << 7) + lk8;
    }
    const unsigned short* wb = Wt + (lane << 3);

    f32x4 acc[8];
#pragma unroll
    for (int n = 0; n < 8; n++)
#pragma unroll
        for (int j = 0; j < 4; j++) acc[n][j] = 0.f;

#pragma unroll 2
    for (int ks = 0; ks < 4; ks++) {
        bf16x8 af, bn[8];
        if (ABF16) af = *(const bf16x8*)(Abr + ks * 32);
        else {
            float4 a = *(const float4*)(Afr + ks * 32);
            float4 b = *(const float4*)(Afr + ks * 32 + 4);
            af[0]=(short)f2bf(a.x); af[1]=(short)f2bf(a.y); af[2]=(short)f2bf(a.z); af[3]=(short)f2bf(a.w);
            af[4]=(short)f2bf(b.x); af[5]=(short)f2bf(b.y); af[6]=(short)f2bf(b.z); af[7]=(short)f2bf(b.w);
        }
#pragma unroll
        for (int n = 0; n < 8; n++)
            bn[n] = *(const bf16x8*)(wb + ((((ks << 3) + n)) << 9));
#pragma unroll
        for (int n = 0; n < 8; n++)
            acc[n] = __builtin_amdgcn_mfma_f32_16x16x32_bf16(af, bn[n], acc[n], 0, 0, 0);
    }

    const int cbase = lr * 8;
    float bv[8];
    if (BIAS) {
        float4 b0 = *(const float4*)(bias + cbase);
        float4 b1 = *(const float4*)(bias + cbase + 4);
        bv[0]=b0.x; bv[1]=b0.y; bv[2]=b0.z; bv[3]=b0.w;
        bv[4]=b1.x; bv[5]=b1.y; bv[6]=b1.z; bv[7]=b1.w;
    } else {
#pragma unroll
        for (int n = 0; n < 8; n++) bv[n] = 0.f;
    }
    const int rbase = (lane >> 4) * 4;

#pragma unroll
    for (int j = 0; j < 4; j++) {
        int row = row0 + wr + rbase + j;
        bool ok = row < M;
        size_t base = ((size_t)row << 7) + cbase;
        float v[8];
#pragma unroll
        for (int n = 0; n < 8; n++) {
            v[n] = acc[n][j] + bv[n];
            if (TANH) v[n] = tanhf(v[n]);
        }
        if (RESID) {
            if (ok) {
                bf16x8 rv = *(const bf16x8*)(resid_bf + base);
#pragma unroll
                for (int n = 0; n < 8; n++) v[n] += bf2f((unsigned short)rv[n]);
            }
        }
        if (L2) {
            float s = 0.f;
#pragma unroll
            for (int n = 0; n < 8; n++) s += v[n] * v[n];
#pragma unroll
            for (int msk = 8; msk >= 1; msk >>= 1) s += __shfl_xor(s, msk);
            float sc = 1.f / fmaxf(sqrtf(s), 1e-12f);
#pragma unroll
            for (int n = 0; n < 8; n++) v[n] *= sc;
        }
        if (ok) {
            if (F32OUT) {
                *(float4*)(out + base)     = make_float4(v[0], v[1], v[2], v[3]);
                *(float4*)(out + base + 4) = make_float4(v[4], v[5], v[6], v[7]);
            }
            if (BF16OUT) {
                bf16x8 o;
#pragma unroll
                for (int n = 0; n < 8; n++) o[n] = (short)f2bf(v[n]);
                *(bf16x8*)(out_bf + base) = o;
            }
            if (AUX) {
                float ai[8];
                if (AUXBF) {
                    bf16x8 av = *(const bf16x8*)((const unsigned short*)aux_in + base);
#pragma unroll
                    for (int n = 0; n < 8; n++) ai[n] = bf2f((unsigned short)av[n]);
                } else {
                    float4 a0 = *(const float4*)((const float*)aux_in + base);
                    float4 a1 = *(const float4*)((const float*)aux_in + base + 4);
                    ai[0]=a0.x; ai[1]=a0.y; ai[2]=a0.z; ai[3]=a0.w;
                    ai[4]=a1.x; ai[5]=a1.y; ai[6]=a1.z; ai[7]=a1.w;
                }
                *(float4*)(aux_out + base)     = make_float4(ai[0]+v[0], ai[1]+v[1], ai[2]+v[2], ai[3]+v[3]);
                *(float4*)(aux_out + base + 4) = make_float4(ai[4]+v[4], ai[5]+v[5], ai[6]+v[6], ai[7]+v[7]);
            }
        }
    }
}

// ============ fused tail (fragment-major weights) ============
__global__ __launch_bounds__(256)
void tail_fused(const unsigned short* __restrict__ h_bf, const float* __restrict__ accf,
                const unsigned short* __restrict__ Wt7,
                const float* __restrict__ bemb, const float* __restrict__ bl,
                const float* __restrict__ br,
                float* __restrict__ embO, float* __restrict__ lftO,
                float* __restrict__ rgtO, int M)
{
    __shared__ __align__(16) unsigned short ldsA[4][16][136];  // n1
    __shared__ __align__(16) unsigned short ldsB[4][16][136];  // acc / lft0 / rgt0

    const int tid = threadIdx.x;
    const int wv = tid >> 6, lane = tid & 63;
    const int lr = lane & 15;
    const int lk8 = (lane >> 4) * 8;
    const int rbase = (lane >> 4) * 4;
    const int row0 = blockIdx.x * 64 + wv * 16;
    const int cbase = lr * 8;

    const unsigned short* Wg1t  = Wt7 + 1 * 16384 + (lane << 3);
    const unsigned short* Wembt = Wt7 + 2 * 16384 + (lane << 3);
    const unsigned short* Wl0t  = Wt7 + 3 * 16384 + (lane << 3);
    const unsigned short* Wl1t  = Wt7 + 4 * 16384 + (lane << 3);
    const unsigned short* Wr0t  = Wt7 + 5 * 16384 + (lane << 3);
    const unsigned short* Wr1t  = Wt7 + 6 * 16384 + (lane << 3);

    f32x4 acc[8];

#define ZACC() { _Pragma("unroll") for (int n = 0; n < 8; n++) \
                 _Pragma("unroll") for (int q = 0; q < 4; q++) acc[n][q] = 0.f; }
#define MM128(AFRAG, WPTR)                                                            \
    _Pragma("unroll")                                                                 \
    for (int ks = 0; ks < 4; ks++) {                                                  \
        bf16x8 af = (AFRAG);                                                          \
        bf16x8 bn[8];                                                                 \
        _Pragma("unroll")                                                             \
        for (int n = 0; n < 8; n++)                                                   \
            bn[n] = *(const bf16x8*)((WPTR) + ((((ks << 3) + n)) << 9));              \
        _Pragma("unroll")                                                             \
        for (int n = 0; n < 8; n++)                                                   \
            acc[n] = __builtin_amdgcn_mfma_f32_16x16x32_bf16(af, bn[n], acc[n], 0, 0, 0); \
    }
#define LDBIAS(BV, P) { float4 b0_ = *(const float4*)((P) + cbase);                   \
                        float4 b1_ = *(const float4*)((P) + cbase + 4);               \
                        BV[0]=b0_.x; BV[1]=b0_.y; BV[2]=b0_.z; BV[3]=b0_.w;           \
                        BV[4]=b1_.x; BV[5]=b1_.y; BV[6]=b1_.z; BV[7]=b1_.w; }
#define L2NORM(V) { float s_ = 0.f;                                                   \
                    _Pragma("unroll") for (int n = 0; n < 8; n++) s_ += V[n]*V[n];    \
                    _Pragma("unroll") for (int mk = 8; mk >= 1; mk >>= 1) s_ += __shfl_xor(s_, mk); \
                    float sc_ = 1.f / fmaxf(sqrtf(s_), 1e-12f);                       \
                    _Pragma("unroll") for (int n = 0; n < 8; n++) V[n] *= sc_; }

    // ---- stage 1: n1 = l2norm(tanh(h @ Wg1)); acc = accf + n1 ----
    const unsigned short* hrow;
    {
        int r = row0 + lr;
        r = r < M ? r : (M - 1);
        hrow = h_bf + ((size_t)r << 7) + lk8;
    }
    ZACC();
    MM128(*(const bf16x8*)(hrow + ks * 32), Wg1t);
#pragma unroll
    for (int j = 0; j < 4; j++) {
        int row = row0 + rbase + j;
        int rc = row < M ? row : (M - 1);
        float v[8];
#pragma unroll
        for (int n = 0; n < 8; n++) v[n] = tanhf(acc[n][j]);
        L2NORM(v);
        bf16x8 o;
#pragma unroll
        for (int n = 0; n < 8; n++) o[n] = (short)f2bf(v[n]);
        *(bf16x8*)&ldsA[wv][rbase + j][cbase] = o;
        float4 a0 = *(const float4*)(accf + ((size_t)rc << 7) + cbase);
        float4 a1 = *(const float4*)(accf + ((size_t)rc << 7) + cbase + 4);
        float av[8] = {a0.x+v[0], a0.y+v[1], a0.z+v[2], a0.w+v[3],
                       a1.x+v[4], a1.y+v[5], a1.z+v[6], a1.w+v[7]};
        bf16x8 ob;
#pragma unroll
        for (int n = 0; n < 8; n++) ob[n] = (short)f2bf(av[n]);
        *(bf16x8*)&ldsB[wv][rbase + j][cbase] = ob;
    }

    // ---- stage 2: emb = l2norm(acc @ Wemb + bemb) ----
    ZACC();
    MM128(*(const bf16x8*)&ldsB[wv][lr][ks * 32 + lk8], Wembt);
    {
        float bv[8]; LDBIAS(bv, bemb);
#pragma unroll
        for (int j = 0; j < 4; j++) {
            int row = row0 + rbase + j;
            float v[8];
#pragma unroll
            for (int n = 0; n < 8; n++) v[n] = acc[n][j] + bv[n];
            L2NORM(v);
            if (row < M) {
                size_t base = ((size_t)row << 7) + cbase;
                *(float4*)(embO + base)     = make_float4(v[0], v[1], v[2], v[3]);
                *(float4*)(embO + base + 4) = make_float4(v[4], v[5], v[6], v[7]);
            }
        }
    }

    // ---- stage 3: lft0 = tanh(n1 @ Wl0 + bl0) + n1 ----
    ZACC();
    MM128(*(const bf16x8*)&ldsA[wv][lr][ks * 32 + lk8], Wl0t);
    {
        float bv[8]; LDBIAS(bv, bl);
#pragma unroll
        for (int j = 0; j < 4; j++) {
            bf16x8 rv = *(const bf16x8*)&ldsA[wv][rbase + j][cbase];
            bf16x8 ob;
#pragma unroll
            for (int n = 0; n < 8; n++)
                ob[n] = (short)f2bf(tanhf(acc[n][j] + bv[n]) + bf2f((unsigned short)rv[n]));
            *(bf16x8*)&ldsB[wv][rbase + j][cbase] = ob;
        }
    }

    // ---- stage 4: lft = tanh(lft0 @ Wl1 + bl1) ----
    ZACC();
    MM128(*(const bf16x8*)&ldsB[wv][lr][ks * 32 + lk8], Wl1t);
    {
        float bv[8]; LDBIAS(bv, bl + 128);
#pragma unroll
        for (int j = 0; j < 4; j++) {
            int row = row0 + rbase + j;
            if (row < M) {
                size_t base = ((size_t)row << 7) + cbase;
                *(float4*)(lftO + base)     = make_float4(tanhf(acc[0][j]+bv[0]), tanhf(acc[1][j]+bv[1]),
                                                          tanhf(acc[2][j]+bv[2]), tanhf(acc[3][j]+bv[3]));
                *(float4*)(lftO + base + 4) = make_float4(tanhf(acc[4][j]+bv[4]), tanhf(acc[5][j]+bv[5]),
                                                          tanhf(acc[6][j]+bv[6]), tanhf(acc[7][j]+bv[7]));
            }
        }
    }

    // ---- stage 5: rgt0 = tanh(n1 @ Wr0 + br0) + n1 ----
    ZACC();
    MM128(*(const bf16x8*)&ldsA[wv][lr][ks * 32 + lk8], Wr0t);
    {
        float bv[8]; LDBIAS(bv, br);
#pragma unroll
        for (int j = 0; j < 4; j++) {
            bf16x8 rv = *(const bf16x8*)&ldsA[wv][rbase + j][cbase];
            bf16x8 ob;
#pragma unroll
            for (int n = 0; n < 8; n++)
                ob[n] = (short)f2bf(tanhf(acc[n][j] + bv[n]) + bf2f((unsigned short)rv[n]));
            *(bf16x8*)&ldsB[wv][rbase + j][cbase] = ob;
        }
    }

    // ---- stage 6: rgt = tanh(rgt0 @ Wr1 + br1) ----
    ZACC();
    MM128(*(const bf16x8*)&ldsB[wv][lr][ks * 32 + lk8], Wr1t);
    {
        float bv[8]; LDBIAS(bv, br + 128);
#pragma unroll
        for (int j = 0; j < 4; j++) {
            int row = row0 + rbase + j;
            if (row < M) {
                size_t base = ((size_t)row << 7) + cbase;
                *(float4*)(rgtO + base)     = make_float4(tanhf(acc[0][j]+bv[0]), tanhf(acc[1][j]+bv[1]),
                                                          tanhf(acc[2][j]+bv[2]), tanhf(acc[3][j]+bv[3]));
                *(float4*)(rgtO + base + 4) = make_float4(tanhf(acc[4][j]+bv[4]), tanhf(acc[5][j]+bv[5]),
                                                          tanhf(acc[6][j]+bv[6]), tanhf(acc[7][j]+bv[7]));
            }
        }
    }
#undef ZACC
#undef MM128
#undef LDBIAS
#undef L2NORM
}

// ============ bucketed CSR build ============
#define RCHUNK 16384

__global__ __launch_bounds__(256)
void bhist_k(const int* __restrict__ rows, int* __restrict__ bcnt, int E, int NB)
{
    __shared__ int lc[1024];
    for (int b = threadIdx.x; b < NB; b += 256) lc[b] = 0;
    __syncthreads();
    int start = blockIdx.x * RCHUNK;
    int end = min(start + RCHUNK, E);
    for (int i = start + threadIdx.x; i < end; i += 256)
        atomicAdd(&lc[rows[i] >> 7], 1);
    __syncthreads();
    for (int b = threadIdx.x; b < NB; b += 256)
        if (lc[b]) atomicAdd(&bcnt[b], lc[b]);
}

__global__ __launch_bounds__(256)
void bucket_scan(const int* __restrict__ bcnt, int* __restrict__ bbase,
                 int* __restrict__ bcur, int NB)
{
    __shared__ int sdata[256];
    const int tid = threadIdx.x;
    int loc[4]; int s = 0;
#pragma unroll
    for (int j = 0; j < 4; j++) {
        int i = tid * 4 + j;
        int v = (i < NB) ? bcnt[i] : 0;
        loc[j] = s; s += v;
    }
    sdata[tid] = s;
    __syncthreads();
    int x = s;
    for (int off = 1; off < 256; off <<= 1) {
        int t = 0;
        if (tid >= off) t = sdata[tid - off];
        __syncthreads();
        x += t;
        sdata[tid] = x;
        __syncthreads();
    }
    int excl = x - s;
#pragma unroll
    for (int j = 0; j < 4; j++) {
        int i = tid * 4 + j;
        if (i < NB) { bbase[i] = excl + loc[j]; bcur[i] = excl + loc[j]; }
    }
    if (tid == 255) bbase[NB] = x;
}

__global__ __launch_bounds__(256)
void bucket_scatter(const int* __restrict__ rows, const int* __restrict__ cols,
                    const float* __restrict__ vals, int* __restrict__ bcur,
                    int2* __restrict__ tmp, int E, int NB)
{
    __shared__ int lcnt[1024];
    __shared__ int lbase[1024];
    for (int b = threadIdx.x; b < NB; b += 256) lcnt[b] = 0;
    __syncthreads();
    int start = blockIdx.x * RCHUNK;
    int end = min(start + RCHUNK, E);
    for (int i = start + threadIdx.x; i < end; i += 256)
        atomicAdd(&lcnt[rows[i] >> 7], 1);
    __syncthreads();
    for (int b = threadIdx.x; b < NB; b += 256) {
        int c = lcnt[b];
        lbase[b] = c ? atomicAdd(&bcur[b], c) : 0;
        lcnt[b] = 0;
    }
    __syncthreads();
    for (int i = start + threadIdx.x; i < end; i += 256) {
        int r = rows[i];
        int b = r >> 7;
        int off = atomicAdd(&lcnt[b], 1);
        tmp[lbase[b] + off] = make_int2(cols[i] | ((r & 127) << 17), __float_as_int(vals[i]));
    }
}

__global__ __launch_bounds__(256)
void csr_place(const int2* __restrict__ tmp, const int* __restrict__ bbase,
               int* __restrict__ rowptr, int2* __restrict__ packed, int M, int NB)
{
    __shared__ int lcnt[128];
    __shared__ int lofs[128];
    const int tid = threadIdx.x;
    const int b = blockIdx.x;
    const int s = bbase[b], e = bbase[b + 1];
    const int rb = b << 7;
    if (tid < 128) lcnt[tid] = 0;
    __syncthreads();
    for (int i = s + tid; i < e; i += 256)
        atomicAdd(&lcnt[(((unsigned)tmp[i].x) >> 17) & 127], 1);
    __syncthreads();
    if (tid == 0) {
        int run = s;
#pragma unroll 8
        for (int r = 0; r < 128; r++) { lofs[r] = run; run += lcnt[r]; }
    }
    __syncthreads();
    if (tid < 128 && rb + tid < M) rowptr[rb + tid] = lofs[tid];
    if (b == NB - 1 && tid == 0) rowptr[M] = e;
    if (tid < 128) lcnt[tid] = 0;
    __syncthreads();
    for (int i = s + tid; i < e; i += 256) {
        int2 t = tmp[i];
        int rl = (((unsigned)t.x) >> 17) & 127;
        int pos = lofs[rl] + atomicAdd(&lcnt[rl], 1);
        packed[pos] = make_int2(t.x & 0x1FFFF, t.y);
    }
}

// ============ CSR SpMM: 16 lanes/edge x 4 edge-groups, 16B gathers ============
__global__ __launch_bounds__(256)
void spmm_csr(const int* __restrict__ rowptr, const int2* __restrict__ packed,
              const unsigned short* __restrict__ embb, unsigned short* __restrict__ hb, int N)
{
    const int wv = threadIdx.x >> 6, lane = threadIdx.x & 63;
    const int g = lane >> 4, q = lane & 15;
    const int r = blockIdx.x * 4 + wv;
    if (r >= N) return;
    const int s = rowptr[r], e = rowptr[r + 1];
    const unsigned short* __restrict__ eb = embb + q * 8;

    float a0=0.f,a1=0.f,a2=0.f,a3=0.f,a4=0.f,a5=0.f,a6=0.f,a7=0.f;
    int i = s + g;
    for (; i + 12 < e; i += 16) {
#pragma unroll
        for (int u = 0; u < 4; u++) {
            int2 p = packed[i + 4 * u];
            uint4 m = *(const uint4*)(eb + ((size_t)p.x << 7));
            float v = __int_as_float(p.y);
            a0 += v * __uint_as_float(m.x << 16);
            a1 += v * __uint_as_float(m.x & 0xffff0000u);
            a2 += v * __uint_as_float(m.y << 16);
            a3 += v * __uint_as_float(m.y & 0xffff0000u);
            a4 += v * __uint_as_float(m.z << 16);
            a5 += v * __uint_as_float(m.z & 0xffff0000u);
            a6 += v * __uint_as_float(m.w << 16);
            a7 += v * __uint_as_float(m.w & 0xffff0000u);
        }
    }
    for (; i < e; i += 4) {
        int2 p = packed[i];
        uint4 m = *(const uint4*)(eb + ((size_t)p.x << 7));
        float v = __int_as_float(p.y);
        a0 += v * __uint_as_float(m.x << 16);
        a1 += v * __uint_as_float(m.x & 0xffff0000u);
        a2 += v * __uint_as_float(m.y << 16);
        a3 += v * __uint_as_float(m.y & 0xffff0000u);
        a4 += v * __uint_as_float(m.z << 16);
        a5 += v * __uint_as_float(m.z & 0xffff0000u);
        a6 += v * __uint_as_float(m.w << 16);
        a7 += v * __uint_as_float(m.w & 0xffff0000u);
    }
#pragma unroll
    for (int msk = 16; msk <= 32; msk <<= 1) {
        a0 += __shfl_xor(a0, msk); a1 += __shfl_xor(a1, msk);
        a2 += __shfl_xor(a2, msk); a3 += __shfl_xor(a3, msk);
        a4 += __shfl_xor(a4, msk); a5 += __shfl_xor(a5, msk);
        a6 += __shfl_xor(a6, msk); a7 += __shfl_xor(a7, msk);
    }
    if (g == 0) {
        unsigned o0 = (unsigned)f2bf(a0) | ((unsigned)f2bf(a1) << 16);
        unsigned o1 = (unsigned)f2bf(a2) | ((unsigned)f2bf(a3) << 16);
        unsigned o2 = (unsigned)f2bf(a4) | ((unsigned)f2bf(a5) << 16);
        unsigned o3 = (unsigned)f2bf(a6) | ((unsigned)f2bf(a7) << 16);
        *(uint4*)(hb + ((size_t)r << 7) + q * 8) = make_uint4(o0, o1, o2, o3);
    }
}

// ============ launch ============
extern "C" void kernel_launch(void* const* d_in, const int* in_sizes, int n_in,
                              void* d_out, int out_size, void* d_ws, size_t ws_size,
                              hipStream_t stream)
{
    const float* feat  = (const float*)d_in[0];
    const int*   srows = (const int*)  d_in[1];
    const int*   scols = (const int*)  d_in[2];
    const float* svals = (const float*)d_in[3];
    const float* Wf0   = (const float*)d_in[4];
    const float* bf0   = (const float*)d_in[5];
    const float* Wf1   = (const float*)d_in[6];
    const float* bf1   = (const float*)d_in[7];
    const float* Wg    = (const float*)d_in[8];
    const float* Wemb  = (const float*)d_in[9];
    const float* bemb  = (const float*)d_in[10];
    const float* Wl    = (const float*)d_in[11];
    const float* bl    = (const float*)d_in[12];
    const float* Wr    = (const float*)d_in[13];
    const float* br    = (const float*)d_in[14];

    const int M = in_sizes[0] / 512;   // 100000 nodes
    const int E = in_sizes[1];         // 3200000 edges
    const int NB = (M + 127) >> 7;     // 782 buckets

    float* out = (float*)d_out;
    float* R0 = out;
    float* R1 = out + (size_t)M * 128;
    float* R2 = out + (size_t)M * 256;

    // ---- ws layout ----
    float* ws = (float*)d_ws;
    float* accf = ws;                                      // [M,128] f32; tmp aliases (dead before s4)
    int2*  tmp  = (int2*)ws;
    int*   ip = (int*)(ws + (size_t)M * 128);
    int*   rowptr  = ip;                                   // M+1
    int2*  packed  = (int2*)(ip + (((size_t)M + 4) & ~(size_t)3));  // E
    int*   bcnt    = (int*)(packed + E);                   // 1024
    int*   bbase   = bcnt + 1024;                          // 1032
    int*   bcur    = bbase + 1032;                         // 1024
    unsigned short* h_ws = (unsigned short*)(bcur + 1024); // [M,128] bf16 spmm accumulator
    unsigned short* Wt0  = h_ws + (size_t)M * 128;         // [256x512] frag-major D
    unsigned short* Wt1  = Wt0 + 256 * 512;                // [128x256] frag-major D
    unsigned short* Wt7  = Wt1 + 128 * 256;                // 7 x [128x128] frag-major E

    // ---- d_out scratch timeline ----
    unsigned short* R0a = (unsigned short*)R0;
    unsigned short* R1a = (unsigned short*)R1;
    unsigned short* feat_bf = (unsigned short*)R0;  // [M,512], dead after s1
    unsigned short* x1_bf   = (unsigned short*)R2;  // [M,256], dead after s2
    unsigned short* x_bf    = R0a;                  // s2 out; spmm3 src; s4 aux
    unsigned short* n0_bf   = R1a;                  // s4 -> spmm5

    dim3 blk(256);
    const int gm128 = (M + 127) / 128;
    const int gm64  = (M + 63) / 64;
    const int nch   = (E + RCHUNK - 1) / RCHUNK;

    // weight converts
    wconvD<<<(512*256 + 255)/256, blk, 0, stream>>>(Wf0, Wt0, 512, 256);
    wconvD<<<(256*128 + 255)/256, blk, 0, stream>>>(Wf1, Wt1, 256, 128);
    wconv7<<<(7*16384 + 255)/256, blk, 0, stream>>>(Wg, Wemb, Wl, Wr, Wt7);

    // feat -> bf16
    f32_to_bf16<<<(int)(((long)M * 64 + 255) / 256), blk, 0, stream>>>(feat, feat_bf, (long)M * 64);

    // ---- CSR build ----
    hipMemsetAsync(bcnt, 0, (size_t)NB * 4, stream);
    bhist_k<<<nch, blk, 0, stream>>>(srows, bcnt, E, NB);
    bucket_scan<<<1, blk, 0, stream>>>(bcnt, bbase, bcur, NB);
    bucket_scatter<<<nch, blk, 0, stream>>>(srows, scols, svals, bcur, tmp, E, NB);
    csr_place<<<NB, blk, 0, stream>>>(tmp, bbase, rowptr, packed, M, NB);

    // ---- network ----
    mfma_direct<<<dim3(gm128,2),blk,0,stream>>>(feat_bf, Wt0, bf0, x1_bf, M, 512, 256);
    mfma_direct<<<dim3(gm128,1),blk,0,stream>>>(x1_bf, Wt1, bf1, x_bf, M, 256, 128);
    spmm_csr<<<(M + 3) / 4, blk, 0, stream>>>(rowptr, packed, x_bf, h_ws, M);
    mfma_ep<true,true,true,false,true,true,false,true,false><<<gm64,blk,0,stream>>>(
        h_ws, Wt7 /*Wg0 frag-major*/, nullptr, nullptr, x_bf, accf, nullptr, n0_bf, M);
    spmm_csr<<<(M + 3) / 4, blk, 0, stream>>>(rowptr, packed, n0_bf, h_ws, M);
    tail_fused<<<gm64, blk, 0, stream>>>(h_ws, accf, Wt7, bemb, bl, br, R0, R1, R2, M);
}